// Round 5
// baseline (2646.540 us; speedup 1.0000x reference)
//
#include <hip/hip_runtime.h>
#include <hip/hip_fp16.h>

#define IN_F 256
#define OUT_F 128
#define RPB 64          // rows per bucket (32 KB LDS accumulator)
#define LOG_RPB 6
#define MAXB 2048       // max buckets (n_nodes <= 131072)
#define CHUNK 32768     // edges per binning block

// ---------------- K1: sup(fp16) = x @ W  (fp32 accum) -----------------------
__global__ __launch_bounds__(256) void gemm_xw(const float* __restrict__ x,
                                               const float* __restrict__ w,
                                               __half* __restrict__ sup,
                                               int n_nodes) {
  __shared__ float xs[16][IN_F];
  int row0 = blockIdx.x * 16;
  const float4* xg = (const float4*)(x + (size_t)row0 * IN_F);
  float4* xsv = (float4*)&xs[0][0];
#pragma unroll
  for (int i = 0; i < 4; ++i) xsv[threadIdx.x + i * 256] = xg[threadIdx.x + i * 256];
  __syncthreads();

  int c = threadIdx.x & 127;
  int rbase = (threadIdx.x >> 7) * 8;
  float acc[8] = {0.f, 0.f, 0.f, 0.f, 0.f, 0.f, 0.f, 0.f};
  for (int k = 0; k < IN_F; k += 4) {
    float w0 = w[(k + 0) * OUT_F + c];
    float w1 = w[(k + 1) * OUT_F + c];
    float w2 = w[(k + 2) * OUT_F + c];
    float w3 = w[(k + 3) * OUT_F + c];
#pragma unroll
    for (int r = 0; r < 8; ++r) {
      float4 xv = *(const float4*)&xs[rbase + r][k];
      acc[r] = fmaf(xv.x, w0, acc[r]);
      acc[r] = fmaf(xv.y, w1, acc[r]);
      acc[r] = fmaf(xv.z, w2, acc[r]);
      acc[r] = fmaf(xv.w, w3, acc[r]);
    }
  }
#pragma unroll
  for (int r = 0; r < 8; ++r) {
    int row = row0 + rbase + r;
    if (row < n_nodes) sup[(size_t)row * OUT_F + c] = __float2half(acc[r]);
  }
}

// ---------------- bucket hist (LDS-privatized) + scan ------------------------
__global__ __launch_bounds__(256) void bzero(int* __restrict__ p, int n) {
  int i = blockIdx.x * 256 + threadIdx.x;
  if (i < n) p[i] = 0;
}

__global__ __launch_bounds__(256) void bucket_hist(const int* __restrict__ erow,
                                                   int* __restrict__ bcnt,
                                                   int n_edges, int nbuck) {
  __shared__ int h[MAXB];
  int t = threadIdx.x;
  for (int i = t; i < nbuck; i += 256) h[i] = 0;
  __syncthreads();
  int beg = blockIdx.x * CHUNK;
  int end = min(beg + CHUNK, n_edges);
  for (int e = beg + t; e < end; e += 256) atomicAdd(&h[erow[e] >> LOG_RPB], 1);
  __syncthreads();
  for (int i = t; i < nbuck; i += 256)
    if (h[i]) atomicAdd(&bcnt[i], h[i]);
}

// single block, 1024 threads, 2 buckets per thread (nbuck <= 2048)
__global__ __launch_bounds__(1024) void bucket_scan(const int* __restrict__ bcnt,
                                                    int* __restrict__ bptr,
                                                    int* __restrict__ gcur, int nbuck) {
  __shared__ int sc[1024];
  int t = threadIdx.x;
  int i0 = 2 * t, i1 = 2 * t + 1;
  int c0 = (i0 < nbuck) ? bcnt[i0] : 0;
  int c1 = (i1 < nbuck) ? bcnt[i1] : 0;
  int s = c0 + c1;
  sc[t] = s;
  __syncthreads();
  for (int off = 1; off < 1024; off <<= 1) {
    int u = (t >= off) ? sc[t - off] : 0;
    __syncthreads();
    sc[t] += u;
    __syncthreads();
  }
  int run = sc[t] - s;
  if (i0 < nbuck) { bptr[i0] = run; gcur[i0] = run; run += c0; }
  if (i1 < nbuck) { bptr[i1] = run; gcur[i1] = run; run += c1; }
  if (t == 1023) bptr[nbuck] = sc[1023];
}

// ---------------- coarse binning with per-block run reservation -------------
// tmp[pos] = { col | (rowlocal<<17), val_bits }, grouped by bucket.
__global__ __launch_bounds__(256) void coarse_bin(const int* __restrict__ erow,
                                                  const int* __restrict__ ecol,
                                                  const float* __restrict__ eval,
                                                  int* __restrict__ gcur,
                                                  int2* __restrict__ tmp,
                                                  int n_edges, int nbuck) {
  __shared__ int cnt[MAXB];
  __shared__ int base[MAXB];
  int t = threadIdx.x;
  for (int i = t; i < nbuck; i += 256) cnt[i] = 0;
  __syncthreads();
  int beg = blockIdx.x * CHUNK;
  int end = min(beg + CHUNK, n_edges);
  // phase a: block-local bucket histogram (LDS)
  for (int e = beg + t; e < end; e += 256) atomicAdd(&cnt[erow[e] >> LOG_RPB], 1);
  __syncthreads();
  // phase b: reserve contiguous runs in the global bucket regions
  for (int i = t; i < nbuck; i += 256) {
    int c = cnt[i];
    base[i] = (c > 0) ? atomicAdd(&gcur[i], c) : 0;
    cnt[i] = 0;  // reuse as local cursor
  }
  __syncthreads();
  // phase c: scatter into reserved runs
  for (int e = beg + t; e < end; e += 256) {
    int r = erow[e];
    int b = r >> LOG_RPB;
    int pos = base[b] + atomicAdd(&cnt[b], 1);
    int2 pk;
    pk.x = ecol[e] | ((r & (RPB - 1)) << 17);
    pk.y = __float_as_int(eval[e]);
    tmp[pos] = pk;
  }
}

// ---------------- fused: LDS-accumulating gather + bias + relu --------------
// one block per 64-row bucket; edges need no ordering within the bucket.
__global__ __launch_bounds__(256) void bucket_gather(const int* __restrict__ bptr,
                                                     const int2* __restrict__ tmp,
                                                     const __half* __restrict__ sup,
                                                     const float* __restrict__ bias,
                                                     float* __restrict__ out,
                                                     int n_nodes) {
  __shared__ float acc[RPB][OUT_F];  // 32 KB
  int b = blockIdx.x;
  int row0 = b << LOG_RPB;
  int nr = min(RPB, n_nodes - row0);
  int t = threadIdx.x;
  // zero the accumulator
  float4* av = (float4*)&acc[0][0];
#pragma unroll
  for (int i = 0; i < RPB * OUT_F / 4 / 256; ++i)
    av[t + i * 256] = float4{0.f, 0.f, 0.f, 0.f};
  __syncthreads();

  int beg = bptr[b];
  int end = bptr[b + 1];
  int lane = t & 63;
  int wv = t >> 6;
  // contiguous slice per wave
  int cntE = end - beg;
  int per = (cntE + 3) >> 2;
  int wbeg = beg + wv * per;
  int wend = min(wbeg + per, end);

  int j = wbeg;
  for (; j + 1 < wend; j += 2) {
    int2 e0 = tmp[j];
    int2 e1 = tmp[j + 1];
    int c0 = e0.x & 0x1FFFF;
    int c1 = e1.x & 0x1FFFF;
    __half2 s0 = ((const __half2*)(sup + (size_t)c0 * OUT_F))[lane];
    __half2 s1 = ((const __half2*)(sup + (size_t)c1 * OUT_F))[lane];
    int rl0 = e0.x >> 17;
    int rl1 = e1.x >> 17;
    float v0 = __int_as_float(e0.y);
    float v1 = __int_as_float(e1.y);
    float2 f0 = __half22float2(s0);
    float2 f1 = __half22float2(s1);
    atomicAdd(&acc[rl0][2 * lane + 0], f0.x * v0);
    atomicAdd(&acc[rl0][2 * lane + 1], f0.y * v0);
    atomicAdd(&acc[rl1][2 * lane + 0], f1.x * v1);
    atomicAdd(&acc[rl1][2 * lane + 1], f1.y * v1);
  }
  if (j < wend) {
    int2 e0 = tmp[j];
    int c0 = e0.x & 0x1FFFF;
    __half2 s0 = ((const __half2*)(sup + (size_t)c0 * OUT_F))[lane];
    int rl0 = e0.x >> 17;
    float v0 = __int_as_float(e0.y);
    float2 f0 = __half22float2(s0);
    atomicAdd(&acc[rl0][2 * lane + 0], f0.x * v0);
    atomicAdd(&acc[rl0][2 * lane + 1], f0.y * v0);
  }
  __syncthreads();

  // epilogue: bias + relu + store
  float2 bia = ((const float2*)bias)[lane];
  for (int rl = wv; rl < nr; rl += 4) {
    float2 o;
    o.x = fmaxf(acc[rl][2 * lane + 0] + bia.x, 0.f);
    o.y = fmaxf(acc[rl][2 * lane + 1] + bia.y, 0.f);
    ((float2*)(out + (size_t)(row0 + rl) * OUT_F))[lane] = o;
  }
}

// ---------------- fallback (atomic scatter) ---------------------------------
__global__ __launch_bounds__(256) void init_bias(float* __restrict__ out,
                                                 const float* __restrict__ bias,
                                                 int total) {
  int i = blockIdx.x * 256 + threadIdx.x;
  if (i < total) out[i] = bias[i & (OUT_F - 1)];
}

__global__ __launch_bounds__(256) void spmm_scatter(const int* __restrict__ erow,
                                                    const int* __restrict__ ecol,
                                                    const float* __restrict__ eval,
                                                    const __half* __restrict__ sup,
                                                    float* __restrict__ out,
                                                    int n_edges) {
  long long t = (long long)blockIdx.x * 256 + threadIdx.x;
  int e = (int)(t >> 6);
  if (e >= n_edges) return;
  int lane = (int)(t & 63);
  int r = erow[e];
  int c = ecol[e];
  float v = eval[e];
  __half2 s = ((const __half2*)(sup + (size_t)c * OUT_F))[lane];
  float2 f = __half22float2(s);
  float* orow = out + (size_t)r * OUT_F + 2 * lane;
  unsafeAtomicAdd(orow + 0, f.x * v);
  unsafeAtomicAdd(orow + 1, f.y * v);
}

__global__ __launch_bounds__(256) void relu_k(float* __restrict__ out, int total) {
  int i = blockIdx.x * 256 + threadIdx.x;
  if (i < total) out[i] = fmaxf(out[i], 0.f);
}

extern "C" void kernel_launch(void* const* d_in, const int* in_sizes, int n_in,
                              void* d_out, int out_size, void* d_ws, size_t ws_size,
                              hipStream_t stream) {
  const float* x = (const float*)d_in[0];
  const int* erow = (const int*)d_in[1];
  const int* ecol = (const int*)d_in[2];
  const float* eval = (const float*)d_in[3];
  const float* w = (const float*)d_in[4];
  const float* bias = (const float*)d_in[5];
  float* out = (float*)d_out;

  int n_nodes = in_sizes[0] / IN_F;   // 100000
  int n_edges = in_sizes[1];          // 3200000
  int total = n_nodes * OUT_F;
  int nbuck = (n_nodes + RPB - 1) >> LOG_RPB;

  // ws layout
  char* p = (char*)d_ws;
  __half* sup = (__half*)p;             p += (size_t)n_nodes * OUT_F * 2;
  int2* tmp = (int2*)p;                 p += (size_t)n_edges * 8;
  int* bcnt = (int*)p;                  p += (size_t)nbuck * 4;
  int* bptr = (int*)p;                  p += (size_t)(nbuck + 1) * 4;
  int* gcur = (int*)p;                  p += (size_t)nbuck * 4;
  size_t need = (size_t)(p - (char*)d_ws);

  // K1: support = x @ W  (fp16 out)
  gemm_xw<<<(n_nodes + 15) / 16, 256, 0, stream>>>(x, w, sup, n_nodes);

  if (ws_size >= need && nbuck <= MAXB) {
    int ebl = (n_edges + CHUNK - 1) / CHUNK;
    bzero<<<(nbuck + 255) / 256, 256, 0, stream>>>(bcnt, nbuck);
    bucket_hist<<<ebl, 256, 0, stream>>>(erow, bcnt, n_edges, nbuck);
    bucket_scan<<<1, 1024, 0, stream>>>(bcnt, bptr, gcur, nbuck);
    coarse_bin<<<ebl, 256, 0, stream>>>(erow, ecol, eval, gcur, tmp, n_edges, nbuck);
    bucket_gather<<<nbuck, 256, 0, stream>>>(bptr, tmp, sup, bias, out, n_nodes);
  } else {
    init_bias<<<(total + 255) / 256, 256, 0, stream>>>(out, bias, total);
    long long threads = (long long)n_edges * 64;
    spmm_scatter<<<(int)((threads + 255) / 256), 256, 0, stream>>>(erow, ecol, eval,
                                                                   sup, out, n_edges);
    relu_k<<<(total + 255) / 256, 256, 0, stream>>>(out, total);
  }
}

// Round 6
// 453.454 us; speedup vs baseline: 5.8364x; 5.8364x over previous
//
#include <hip/hip_runtime.h>
#include <hip/hip_fp16.h>

#define IN_F 256
#define OUT_F 128
#define RPB 128         // rows per bucket
#define LOG_RPB 7
#define MAXB 1024       // max buckets (n_nodes <= 131072)
#define CHUNK 32768     // edges per binning block

// ---------------- K1: sup(fp16) = x @ W  (fp32 accum) -----------------------
__global__ __launch_bounds__(256) void gemm_xw(const float* __restrict__ x,
                                               const float* __restrict__ w,
                                               __half* __restrict__ sup,
                                               int n_nodes) {
  __shared__ float xs[16][IN_F];
  int row0 = blockIdx.x * 16;
  const float4* xg = (const float4*)(x + (size_t)row0 * IN_F);
  float4* xsv = (float4*)&xs[0][0];
#pragma unroll
  for (int i = 0; i < 4; ++i) xsv[threadIdx.x + i * 256] = xg[threadIdx.x + i * 256];
  __syncthreads();

  int c = threadIdx.x & 127;
  int rbase = (threadIdx.x >> 7) * 8;
  float acc[8] = {0.f, 0.f, 0.f, 0.f, 0.f, 0.f, 0.f, 0.f};
  for (int k = 0; k < IN_F; k += 4) {
    float w0 = w[(k + 0) * OUT_F + c];
    float w1 = w[(k + 1) * OUT_F + c];
    float w2 = w[(k + 2) * OUT_F + c];
    float w3 = w[(k + 3) * OUT_F + c];
#pragma unroll
    for (int r = 0; r < 8; ++r) {
      float4 xv = *(const float4*)&xs[rbase + r][k];
      acc[r] = fmaf(xv.x, w0, acc[r]);
      acc[r] = fmaf(xv.y, w1, acc[r]);
      acc[r] = fmaf(xv.z, w2, acc[r]);
      acc[r] = fmaf(xv.w, w3, acc[r]);
    }
  }
#pragma unroll
  for (int r = 0; r < 8; ++r) {
    int row = row0 + rbase + r;
    if (row < n_nodes) sup[(size_t)row * OUT_F + c] = __float2half(acc[r]);
  }
}

// ---------------- bucket hist (LDS-privatized) + scan ------------------------
__global__ __launch_bounds__(256) void bzero(int* __restrict__ p, int n) {
  int i = blockIdx.x * 256 + threadIdx.x;
  if (i < n) p[i] = 0;
}

__global__ __launch_bounds__(256) void bucket_hist(const int* __restrict__ erow,
                                                   int* __restrict__ bcnt,
                                                   int n_edges, int nbuck) {
  __shared__ int h[MAXB];
  int t = threadIdx.x;
  for (int i = t; i < nbuck; i += 256) h[i] = 0;
  __syncthreads();
  int beg = blockIdx.x * CHUNK;
  int end = min(beg + CHUNK, n_edges);
  for (int e = beg + t; e < end; e += 256) atomicAdd(&h[erow[e] >> LOG_RPB], 1);
  __syncthreads();
  for (int i = t; i < nbuck; i += 256)
    if (h[i]) atomicAdd(&bcnt[i], h[i]);
}

// single block, 1024 threads (nbuck <= 1024)
__global__ __launch_bounds__(1024) void bucket_scan(const int* __restrict__ bcnt,
                                                    int* __restrict__ bptr,
                                                    int* __restrict__ gcur, int nbuck) {
  __shared__ int sc[1024];
  int t = threadIdx.x;
  int v = (t < nbuck) ? bcnt[t] : 0;
  sc[t] = v;
  __syncthreads();
  for (int off = 1; off < 1024; off <<= 1) {
    int u = (t >= off) ? sc[t - off] : 0;
    __syncthreads();
    sc[t] += u;
    __syncthreads();
  }
  if (t < nbuck) {
    int ex = sc[t] - v;
    bptr[t] = ex;
    gcur[t] = ex;
  }
  if (t == 1023) bptr[nbuck] = sc[1023];
}

// ---------------- coarse binning with per-block run reservation -------------
// tmp[pos] = { col | (rowlocal<<17), val_bits }, grouped by bucket.
__global__ __launch_bounds__(256) void coarse_bin(const int* __restrict__ erow,
                                                  const int* __restrict__ ecol,
                                                  const float* __restrict__ eval,
                                                  int* __restrict__ gcur,
                                                  int2* __restrict__ tmp,
                                                  int n_edges, int nbuck) {
  __shared__ int cnt[MAXB];
  __shared__ int base[MAXB];
  int t = threadIdx.x;
  for (int i = t; i < nbuck; i += 256) cnt[i] = 0;
  __syncthreads();
  int beg = blockIdx.x * CHUNK;
  int end = min(beg + CHUNK, n_edges);
  for (int e = beg + t; e < end; e += 256) atomicAdd(&cnt[erow[e] >> LOG_RPB], 1);
  __syncthreads();
  for (int i = t; i < nbuck; i += 256) {
    int c = cnt[i];
    base[i] = (c > 0) ? atomicAdd(&gcur[i], c) : 0;
    cnt[i] = 0;  // reuse as local cursor
  }
  __syncthreads();
  for (int e = beg + t; e < end; e += 256) {
    int r = erow[e];
    int b = r >> LOG_RPB;
    int pos = base[b] + atomicAdd(&cnt[b], 1);
    int2 pk;
    pk.x = ecol[e] | ((r & (RPB - 1)) << 17);
    pk.y = __float_as_int(eval[e]);
    tmp[pos] = pk;
  }
}

// ---------------- fine sort: bucket -> row-sorted pedge + row_ptr -----------
// one block per bucket; integer LDS atomics only (native ds ops).
__global__ __launch_bounds__(256) void fine_sort(const int* __restrict__ bptr,
                                                 const int2* __restrict__ tmp,
                                                 int2* __restrict__ pedge,
                                                 int* __restrict__ row_ptr,
                                                 int n_nodes, int nbuck) {
  __shared__ int hist[RPB];
  __shared__ int sc[RPB];
  __shared__ int cur[RPB];
  int b = blockIdx.x;
  int row0 = b << LOG_RPB;
  int t = threadIdx.x;
  int bbeg = bptr[b];
  int bend = bptr[b + 1];

  if (t < RPB) hist[t] = 0;
  __syncthreads();
  for (int j = bbeg + t; j < bend; j += 256) atomicAdd(&hist[tmp[j].x >> 17], 1);
  __syncthreads();
  if (t < RPB) sc[t] = hist[t];
  __syncthreads();
  for (int off = 1; off < RPB; off <<= 1) {
    int u = (t < RPB && t >= off) ? sc[t - off] : 0;
    __syncthreads();
    if (t < RPB) sc[t] += u;
    __syncthreads();
  }
  if (t < RPB) {
    int st = bbeg + sc[t] - hist[t];  // exclusive start, absolute
    cur[t] = st;
    if (row0 + t < n_nodes) row_ptr[row0 + t] = st;
  }
  __syncthreads();
  for (int j = bbeg + t; j < bend; j += 256) {
    int2 e = tmp[j];
    int rl = e.x >> 17;
    int pos = atomicAdd(&cur[rl], 1);
    int2 pk;
    pk.x = e.x & 0x1FFFF;
    pk.y = e.y;
    pedge[pos] = pk;
  }
  if (b == nbuck - 1 && t == 0) row_ptr[n_nodes] = bend;
}

// ---------------- gather: out[r] = relu(bias + sum_j val*sup[col]) ----------
// one wave per row, register accumulation, unroll x4 for MLP.
__global__ __launch_bounds__(256) void spmm_gather(const int* __restrict__ row_ptr,
                                                   const int2* __restrict__ pedge,
                                                   const __half* __restrict__ sup,
                                                   const float* __restrict__ bias,
                                                   float* __restrict__ out,
                                                   int n_nodes) {
  int r = blockIdx.x * 4 + (threadIdx.x >> 6);
  if (r >= n_nodes) return;
  int lane = threadIdx.x & 63;
  int beg = row_ptr[r];
  int end = row_ptr[r + 1];
  float a0x = 0.f, a0y = 0.f, a1x = 0.f, a1y = 0.f;
  float a2x = 0.f, a2y = 0.f, a3x = 0.f, a3y = 0.f;
  int j = beg;
  for (; j + 3 < end; j += 4) {
    int2 e0 = pedge[j];
    int2 e1 = pedge[j + 1];
    int2 e2 = pedge[j + 2];
    int2 e3 = pedge[j + 3];
    __half2 s0 = ((const __half2*)(sup + (size_t)e0.x * OUT_F))[lane];
    __half2 s1 = ((const __half2*)(sup + (size_t)e1.x * OUT_F))[lane];
    __half2 s2 = ((const __half2*)(sup + (size_t)e2.x * OUT_F))[lane];
    __half2 s3 = ((const __half2*)(sup + (size_t)e3.x * OUT_F))[lane];
    float2 f0 = __half22float2(s0);
    float2 f1 = __half22float2(s1);
    float2 f2 = __half22float2(s2);
    float2 f3 = __half22float2(s3);
    float v0 = __int_as_float(e0.y);
    float v1 = __int_as_float(e1.y);
    float v2 = __int_as_float(e2.y);
    float v3 = __int_as_float(e3.y);
    a0x = fmaf(f0.x, v0, a0x); a0y = fmaf(f0.y, v0, a0y);
    a1x = fmaf(f1.x, v1, a1x); a1y = fmaf(f1.y, v1, a1y);
    a2x = fmaf(f2.x, v2, a2x); a2y = fmaf(f2.y, v2, a2y);
    a3x = fmaf(f3.x, v3, a3x); a3y = fmaf(f3.y, v3, a3y);
  }
  for (; j < end; ++j) {
    int2 e0 = pedge[j];
    __half2 s0 = ((const __half2*)(sup + (size_t)e0.x * OUT_F))[lane];
    float2 f0 = __half22float2(s0);
    float v0 = __int_as_float(e0.y);
    a0x = fmaf(f0.x, v0, a0x); a0y = fmaf(f0.y, v0, a0y);
  }
  float ax = (a0x + a1x) + (a2x + a3x);
  float ay = (a0y + a1y) + (a2y + a3y);
  float2 b = ((const float2*)bias)[lane];
  float2 o;
  o.x = fmaxf(ax + b.x, 0.f);
  o.y = fmaxf(ay + b.y, 0.f);
  ((float2*)(out + (size_t)r * OUT_F))[lane] = o;
}

// ---------------- fallback (atomic scatter) ---------------------------------
__global__ __launch_bounds__(256) void init_bias(float* __restrict__ out,
                                                 const float* __restrict__ bias,
                                                 int total) {
  int i = blockIdx.x * 256 + threadIdx.x;
  if (i < total) out[i] = bias[i & (OUT_F - 1)];
}

__global__ __launch_bounds__(256) void spmm_scatter(const int* __restrict__ erow,
                                                    const int* __restrict__ ecol,
                                                    const float* __restrict__ eval,
                                                    const __half* __restrict__ sup,
                                                    float* __restrict__ out,
                                                    int n_edges) {
  long long t = (long long)blockIdx.x * 256 + threadIdx.x;
  int e = (int)(t >> 6);
  if (e >= n_edges) return;
  int lane = (int)(t & 63);
  int r = erow[e];
  int c = ecol[e];
  float v = eval[e];
  __half2 s = ((const __half2*)(sup + (size_t)c * OUT_F))[lane];
  float2 f = __half22float2(s);
  float* orow = out + (size_t)r * OUT_F + 2 * lane;
  unsafeAtomicAdd(orow + 0, f.x * v);
  unsafeAtomicAdd(orow + 1, f.y * v);
}

__global__ __launch_bounds__(256) void relu_k(float* __restrict__ out, int total) {
  int i = blockIdx.x * 256 + threadIdx.x;
  if (i < total) out[i] = fmaxf(out[i], 0.f);
}

extern "C" void kernel_launch(void* const* d_in, const int* in_sizes, int n_in,
                              void* d_out, int out_size, void* d_ws, size_t ws_size,
                              hipStream_t stream) {
  const float* x = (const float*)d_in[0];
  const int* erow = (const int*)d_in[1];
  const int* ecol = (const int*)d_in[2];
  const float* eval = (const float*)d_in[3];
  const float* w = (const float*)d_in[4];
  const float* bias = (const float*)d_in[5];
  float* out = (float*)d_out;

  int n_nodes = in_sizes[0] / IN_F;   // 100000
  int n_edges = in_sizes[1];          // 3200000
  int total = n_nodes * OUT_F;
  int nbuck = (n_nodes + RPB - 1) >> LOG_RPB;

  // ws layout
  char* p = (char*)d_ws;
  __half* sup = (__half*)p;             p += (size_t)n_nodes * OUT_F * 2;
  int2* tmp = (int2*)p;                 p += (size_t)n_edges * 8;
  int2* pedge = (int2*)p;               p += (size_t)n_edges * 8;
  int* row_ptr = (int*)p;               p += (size_t)(n_nodes + 1) * 4;
  int* bcnt = (int*)p;                  p += (size_t)nbuck * 4;
  int* bptr = (int*)p;                  p += (size_t)(nbuck + 1) * 4;
  int* gcur = (int*)p;                  p += (size_t)nbuck * 4;
  size_t need = (size_t)(p - (char*)d_ws);

  // K1: support = x @ W  (fp16 out)
  gemm_xw<<<(n_nodes + 15) / 16, 256, 0, stream>>>(x, w, sup, n_nodes);

  if (ws_size >= need && nbuck <= MAXB) {
    int ebl = (n_edges + CHUNK - 1) / CHUNK;
    bzero<<<(nbuck + 255) / 256, 256, 0, stream>>>(bcnt, nbuck);
    bucket_hist<<<ebl, 256, 0, stream>>>(erow, bcnt, n_edges, nbuck);
    bucket_scan<<<1, 1024, 0, stream>>>(bcnt, bptr, gcur, nbuck);
    coarse_bin<<<ebl, 256, 0, stream>>>(erow, ecol, eval, gcur, tmp, n_edges, nbuck);
    fine_sort<<<nbuck, 256, 0, stream>>>(bptr, tmp, pedge, row_ptr, n_nodes, nbuck);
    spmm_gather<<<(n_nodes + 3) / 4, 256, 0, stream>>>(row_ptr, pedge, sup, bias,
                                                       out, n_nodes);
  } else {
    init_bias<<<(total + 255) / 256, 256, 0, stream>>>(out, bias, total);
    long long threads = (long long)n_edges * 64;
    spmm_scatter<<<(int)((threads + 255) / 256), 256, 0, stream>>>(erow, ecol, eval,
                                                                   sup, out, n_edges);
    relu_k<<<(total + 255) / 256, 256, 0, stream>>>(out, total);
  }
}

// Round 7
// 355.566 us; speedup vs baseline: 7.4432x; 1.2753x over previous
//
#include <hip/hip_runtime.h>
#include <hip/hip_fp16.h>

#define IN_F 256
#define OUT_F 128
#define RPB 128
#define LOG_RPB 7
#define MAXB 1024
#define CHUNK 8192

typedef __attribute__((ext_vector_type(8))) short short8;
typedef __attribute__((ext_vector_type(4))) float f32x4;

__device__ inline short bf16r(float f) {
  unsigned u = __float_as_uint(f);
  u += 0x7FFF + ((u >> 16) & 1);  // RNE
  return (short)(u >> 16);
}

// ---------------- K1: sup(fp16) = x @ W via bf16 MFMA -----------------------
// block = 4 waves, tile 128 rows x 128 cols. W^T staged in LDS (bf16, XOR-
// swizzled 16B granules so 16-lane column reads are conflict-free). A-frags
// straight from global x (fp32 -> bf16 RNE). mfma_f32_16x16x32_bf16:
// A: row=l&15, k=(l>>4)*8+i ; B: col=l&15, same k ; C/D: col=l&15,
// row=(l>>4)*4+reg  [HW-verified layouts].
__global__ __launch_bounds__(256) void gemm_mfma(const float* __restrict__ x,
                                                 const float* __restrict__ w,
                                                 __half* __restrict__ sup,
                                                 int n_nodes) {
  __shared__ short wlds[128 * 256];  // 64 KB: wlds[n][k] swizzled
  int t = threadIdx.x;
  for (int idx = t; idx < 256 * 128; idx += 256) {
    int k = idx >> 7;
    int n = idx & 127;
    int g = k >> 3;
    wlds[n * 256 + ((g ^ (n & 7)) << 3) + (k & 7)] = bf16r(w[idx]);
  }
  __syncthreads();

  int lane = t & 63;
  int wid = t >> 6;
  int wrow = (wid >> 1) * 64;
  int wcol = (wid & 1) * 64;
  int row_blk = blockIdx.x * 128;

  int arow[4];
#pragma unroll
  for (int mt = 0; mt < 4; ++mt)
    arow[mt] = min(row_blk + wrow + mt * 16 + (lane & 15), n_nodes - 1);
  int koff = (lane >> 4) * 8;

  f32x4 acc[4][4];
#pragma unroll
  for (int mt = 0; mt < 4; ++mt)
#pragma unroll
    for (int nt = 0; nt < 4; ++nt) acc[mt][nt] = (f32x4){0.f, 0.f, 0.f, 0.f};

#pragma unroll 2
  for (int kk = 0; kk < IN_F; kk += 32) {
    short8 af[4];
#pragma unroll
    for (int mt = 0; mt < 4; ++mt) {
      const float* px = x + (size_t)arow[mt] * IN_F + kk + koff;
      float4 p = *(const float4*)px;
      float4 q = *(const float4*)(px + 4);
      short8 a;
      a[0] = bf16r(p.x); a[1] = bf16r(p.y); a[2] = bf16r(p.z); a[3] = bf16r(p.w);
      a[4] = bf16r(q.x); a[5] = bf16r(q.y); a[6] = bf16r(q.z); a[7] = bf16r(q.w);
      af[mt] = a;
    }
    short8 bf[4];
    int g = (kk >> 3) + (lane >> 4);
#pragma unroll
    for (int nt = 0; nt < 4; ++nt) {
      int n = wcol + nt * 16 + (lane & 15);
      bf[nt] = *(const short8*)&wlds[n * 256 + ((g ^ (n & 7)) << 3)];
    }
#pragma unroll
    for (int mt = 0; mt < 4; ++mt)
#pragma unroll
      for (int nt = 0; nt < 4; ++nt)
        acc[mt][nt] = __builtin_amdgcn_mfma_f32_16x16x32_bf16(af[mt], bf[nt],
                                                              acc[mt][nt], 0, 0, 0);
  }

#pragma unroll
  for (int mt = 0; mt < 4; ++mt)
#pragma unroll
    for (int nt = 0; nt < 4; ++nt)
#pragma unroll
      for (int reg = 0; reg < 4; ++reg) {
        int grow = row_blk + wrow + mt * 16 + (lane >> 4) * 4 + reg;
        int gcol = wcol + nt * 16 + (lane & 15);
        if (grow < n_nodes)
          sup[(size_t)grow * OUT_F + gcol] = __float2half(acc[mt][nt][reg]);
      }
}

// ---------------- MFMA safety net: sample-check + VALU fixup ----------------
__global__ __launch_bounds__(256) void gemm_check(const float* __restrict__ x,
                                                  const float* __restrict__ w,
                                                  const __half* __restrict__ sup,
                                                  int* __restrict__ flag,
                                                  int n_nodes) {
  int i = blockIdx.x * 256 + threadIdx.x;  // 1024 samples
  int row = (int)(((long long)i * 99991) % n_nodes);
  int col = (i * 37) & (OUT_F - 1);
  float s = 0.f;
  for (int k = 0; k < IN_F; ++k) s += x[(size_t)row * IN_F + k] * w[k * OUT_F + col];
  float got = __half2float(sup[(size_t)row * OUT_F + col]);
  if (fabsf(s - got) > 0.12f) atomicExch(flag, 1);
}

__global__ __launch_bounds__(256) void gemm_fixup(const float* __restrict__ x,
                                                  const float* __restrict__ w,
                                                  __half* __restrict__ sup,
                                                  const int* __restrict__ flag,
                                                  int n_nodes, int ntiles) {
  if (*flag == 0) return;  // uniform early-exit (no barrier crossed)
  __shared__ float xs[16][IN_F];
  for (int tile = blockIdx.x; tile < ntiles; tile += gridDim.x) {
    int row0 = tile * 16;
    const float4* xg = (const float4*)(x + (size_t)row0 * IN_F);
    float4* xsv = (float4*)&xs[0][0];
    __syncthreads();
#pragma unroll
    for (int i = 0; i < 4; ++i) xsv[threadIdx.x + i * 256] = xg[threadIdx.x + i * 256];
    __syncthreads();
    int c = threadIdx.x & 127;
    int rbase = (threadIdx.x >> 7) * 8;
    float acc[8] = {0.f, 0.f, 0.f, 0.f, 0.f, 0.f, 0.f, 0.f};
    for (int k = 0; k < IN_F; k += 4) {
      float w0 = w[(k + 0) * OUT_F + c];
      float w1 = w[(k + 1) * OUT_F + c];
      float w2 = w[(k + 2) * OUT_F + c];
      float w3 = w[(k + 3) * OUT_F + c];
#pragma unroll
      for (int r = 0; r < 8; ++r) {
        float4 xv = *(const float4*)&xs[rbase + r][k];
        acc[r] = fmaf(xv.x, w0, acc[r]);
        acc[r] = fmaf(xv.y, w1, acc[r]);
        acc[r] = fmaf(xv.z, w2, acc[r]);
        acc[r] = fmaf(xv.w, w3, acc[r]);
      }
    }
#pragma unroll
    for (int r = 0; r < 8; ++r) {
      int row = row0 + rbase + r;
      if (row < n_nodes) sup[(size_t)row * OUT_F + c] = __float2half(acc[r]);
    }
  }
}

// ---------------- atomic-free CSR build -------------------------------------
// per-block hist -> cnt2d[bucket][block]
__global__ __launch_bounds__(256) void hist2(const int* __restrict__ erow,
                                             int* __restrict__ cnt2d,
                                             int n_edges, int nbuck, int nblk) {
  __shared__ int h[MAXB];
  int t = threadIdx.x;
  for (int i = t; i < nbuck; i += 256) h[i] = 0;
  __syncthreads();
  int beg = blockIdx.x * CHUNK;
  int end = min(beg + CHUNK, n_edges);
  for (int e = beg + t; e < end; e += 256) atomicAdd(&h[erow[e] >> LOG_RPB], 1);
  __syncthreads();
  for (int i = t; i < nbuck; i += 256) cnt2d[(size_t)i * nblk + blockIdx.x] = h[i];
}

// per-bucket total
__global__ __launch_bounds__(256) void rowsum(const int* __restrict__ cnt2d,
                                              int* __restrict__ bcnt, int nblk) {
  __shared__ int red[256];
  int b = blockIdx.x;
  const int* row = cnt2d + (size_t)b * nblk;
  int t = threadIdx.x;
  int s = 0;
  for (int i = t; i < nblk; i += 256) s += row[i];
  red[t] = s;
  __syncthreads();
  for (int off = 128; off > 0; off >>= 1) {
    if (t < off) red[t] += red[t + off];
    __syncthreads();
  }
  if (t == 0) bcnt[b] = red[0];
}

// exclusive scan of bucket totals -> bptr (nbuck <= 1024)
__global__ __launch_bounds__(1024) void bucket_scan(const int* __restrict__ bcnt,
                                                    int* __restrict__ bptr, int nbuck) {
  __shared__ int sc[1024];
  int t = threadIdx.x;
  int v = (t < nbuck) ? bcnt[t] : 0;
  sc[t] = v;
  __syncthreads();
  for (int off = 1; off < 1024; off <<= 1) {
    int u = (t >= off) ? sc[t - off] : 0;
    __syncthreads();
    sc[t] += u;
    __syncthreads();
  }
  if (t < nbuck) bptr[t] = sc[t] - v;
  if (t == 1023) bptr[nbuck] = sc[1023];
}

// per-bucket prefix over blocks -> off2d[bucket][block]
__global__ __launch_bounds__(256) void rowscan(const int* __restrict__ cnt2d,
                                               const int* __restrict__ bptr,
                                               int* __restrict__ off2d, int nblk) {
  __shared__ int sc[256];
  int b = blockIdx.x;
  const int* row = cnt2d + (size_t)b * nblk;
  int* orow = off2d + (size_t)b * nblk;
  int t = threadIdx.x;
  int chunk = (nblk + 255) >> 8;
  int beg = t * chunk, end2 = min(beg + chunk, nblk);
  int s = 0;
  for (int i = beg; i < end2; ++i) s += row[i];
  sc[t] = s;
  __syncthreads();
  for (int off = 1; off < 256; off <<= 1) {
    int u = (t >= off) ? sc[t - off] : 0;
    __syncthreads();
    sc[t] += u;
    __syncthreads();
  }
  int run = sc[t] - s + bptr[b];
  for (int i = beg; i < end2; ++i) {
    orow[i] = run;
    run += row[i];
  }
}

// bin edges into bucket-grouped tmp using precomputed (atomic-free) bases
__global__ __launch_bounds__(512) void coarse_bin(const int* __restrict__ erow,
                                                  const int* __restrict__ ecol,
                                                  const float* __restrict__ eval,
                                                  const int* __restrict__ off2d,
                                                  int2* __restrict__ tmp,
                                                  int n_edges, int nbuck, int nblk) {
  __shared__ int cnt[MAXB];
  __shared__ int base[MAXB];
  int t = threadIdx.x;
  for (int i = t; i < nbuck; i += 512) {
    cnt[i] = 0;
    base[i] = off2d[(size_t)i * nblk + blockIdx.x];
  }
  __syncthreads();
  int beg = blockIdx.x * CHUNK;
  int end = min(beg + CHUNK, n_edges);
  for (int e = beg + t; e < end; e += 512) {
    int r = erow[e];
    int b = r >> LOG_RPB;
    int pos = base[b] + atomicAdd(&cnt[b], 1);
    int2 pk;
    pk.x = ecol[e] | ((r & (RPB - 1)) << 17);
    pk.y = __float_as_int(eval[e]);
    tmp[pos] = pk;
  }
}

// ---------------- fine sort: bucket -> row-sorted pedge + row_ptr -----------
__global__ __launch_bounds__(256) void fine_sort(const int* __restrict__ bptr,
                                                 const int2* __restrict__ tmp,
                                                 int2* __restrict__ pedge,
                                                 int* __restrict__ row_ptr,
                                                 int n_nodes, int nbuck) {
  __shared__ int hist[RPB];
  __shared__ int sc[RPB];
  __shared__ int cur[RPB];
  int b = blockIdx.x;
  int row0 = b << LOG_RPB;
  int t = threadIdx.x;
  int bbeg = bptr[b];
  int bend = bptr[b + 1];

  if (t < RPB) hist[t] = 0;
  __syncthreads();
  for (int j = bbeg + t; j < bend; j += 256) atomicAdd(&hist[tmp[j].x >> 17], 1);
  __syncthreads();
  if (t < RPB) sc[t] = hist[t];
  __syncthreads();
  for (int off = 1; off < RPB; off <<= 1) {
    int u = (t < RPB && t >= off) ? sc[t - off] : 0;
    __syncthreads();
    if (t < RPB) sc[t] += u;
    __syncthreads();
  }
  if (t < RPB) {
    int st = bbeg + sc[t] - hist[t];
    cur[t] = st;
    if (row0 + t < n_nodes) row_ptr[row0 + t] = st;
  }
  __syncthreads();
  for (int j = bbeg + t; j < bend; j += 256) {
    int2 e = tmp[j];
    int rl = e.x >> 17;
    int pos = atomicAdd(&cur[rl], 1);
    int2 pk;
    pk.x = e.x & 0x1FFFF;
    pk.y = e.y;
    pedge[pos] = pk;
  }
  if (b == nbuck - 1 && t == 0) row_ptr[n_nodes] = bend;
}

// ---------------- gather: out[r] = relu(bias + sum_j val*sup[col]) ----------
__global__ __launch_bounds__(256) void spmm_gather(const int* __restrict__ row_ptr,
                                                   const int2* __restrict__ pedge,
                                                   const __half* __restrict__ sup,
                                                   const float* __restrict__ bias,
                                                   float* __restrict__ out,
                                                   int n_nodes) {
  int r = blockIdx.x * 4 + (threadIdx.x >> 6);
  if (r >= n_nodes) return;
  int lane = threadIdx.x & 63;
  int beg = row_ptr[r];
  int end = row_ptr[r + 1];
  float a0x = 0.f, a0y = 0.f, a1x = 0.f, a1y = 0.f;
  float a2x = 0.f, a2y = 0.f, a3x = 0.f, a3y = 0.f;
  int j = beg;
  for (; j + 3 < end; j += 4) {
    int2 e0 = pedge[j];
    int2 e1 = pedge[j + 1];
    int2 e2 = pedge[j + 2];
    int2 e3 = pedge[j + 3];
    __half2 s0 = ((const __half2*)(sup + (size_t)e0.x * OUT_F))[lane];
    __half2 s1 = ((const __half2*)(sup + (size_t)e1.x * OUT_F))[lane];
    __half2 s2 = ((const __half2*)(sup + (size_t)e2.x * OUT_F))[lane];
    __half2 s3 = ((const __half2*)(sup + (size_t)e3.x * OUT_F))[lane];
    float2 f0 = __half22float2(s0);
    float2 f1 = __half22float2(s1);
    float2 f2 = __half22float2(s2);
    float2 f3 = __half22float2(s3);
    float v0 = __int_as_float(e0.y);
    float v1 = __int_as_float(e1.y);
    float v2 = __int_as_float(e2.y);
    float v3 = __int_as_float(e3.y);
    a0x = fmaf(f0.x, v0, a0x); a0y = fmaf(f0.y, v0, a0y);
    a1x = fmaf(f1.x, v1, a1x); a1y = fmaf(f1.y, v1, a1y);
    a2x = fmaf(f2.x, v2, a2x); a2y = fmaf(f2.y, v2, a2y);
    a3x = fmaf(f3.x, v3, a3x); a3y = fmaf(f3.y, v3, a3y);
  }
  for (; j < end; ++j) {
    int2 e0 = pedge[j];
    __half2 s0 = ((const __half2*)(sup + (size_t)e0.x * OUT_F))[lane];
    float2 f0 = __half22float2(s0);
    float v0 = __int_as_float(e0.y);
    a0x = fmaf(f0.x, v0, a0x); a0y = fmaf(f0.y, v0, a0y);
  }
  float ax = (a0x + a1x) + (a2x + a3x);
  float ay = (a0y + a1y) + (a2y + a3y);
  float2 b = ((const float2*)bias)[lane];
  float2 o;
  o.x = fmaxf(ax + b.x, 0.f);
  o.y = fmaxf(ay + b.y, 0.f);
  ((float2*)(out + (size_t)r * OUT_F))[lane] = o;
}

// ---------------- fallback (atomic scatter) ---------------------------------
__global__ __launch_bounds__(256) void init_bias(float* __restrict__ out,
                                                 const float* __restrict__ bias,
                                                 int total) {
  int i = blockIdx.x * 256 + threadIdx.x;
  if (i < total) out[i] = bias[i & (OUT_F - 1)];
}

__global__ __launch_bounds__(256) void spmm_scatter(const int* __restrict__ erow,
                                                    const int* __restrict__ ecol,
                                                    const float* __restrict__ eval,
                                                    const __half* __restrict__ sup,
                                                    float* __restrict__ out,
                                                    int n_edges) {
  long long t = (long long)blockIdx.x * 256 + threadIdx.x;
  int e = (int)(t >> 6);
  if (e >= n_edges) return;
  int lane = (int)(t & 63);
  int r = erow[e];
  int c = ecol[e];
  float v = eval[e];
  __half2 s = ((const __half2*)(sup + (size_t)c * OUT_F))[lane];
  float2 f = __half22float2(s);
  float* orow = out + (size_t)r * OUT_F + 2 * lane;
  unsafeAtomicAdd(orow + 0, f.x * v);
  unsafeAtomicAdd(orow + 1, f.y * v);
}

__global__ __launch_bounds__(256) void relu_k(float* __restrict__ out, int total) {
  int i = blockIdx.x * 256 + threadIdx.x;
  if (i < total) out[i] = fmaxf(out[i], 0.f);
}

extern "C" void kernel_launch(void* const* d_in, const int* in_sizes, int n_in,
                              void* d_out, int out_size, void* d_ws, size_t ws_size,
                              hipStream_t stream) {
  const float* x = (const float*)d_in[0];
  const int* erow = (const int*)d_in[1];
  const int* ecol = (const int*)d_in[2];
  const float* eval = (const float*)d_in[3];
  const float* w = (const float*)d_in[4];
  const float* bias = (const float*)d_in[5];
  float* out = (float*)d_out;

  int n_nodes = in_sizes[0] / IN_F;   // 100000
  int n_edges = in_sizes[1];          // 3200000
  int total = n_nodes * OUT_F;
  int nbuck = (n_nodes + RPB - 1) >> LOG_RPB;
  int nblk = (n_edges + CHUNK - 1) / CHUNK;

  // ws layout (flag first so fallback path has it too)
  char* p = (char*)d_ws;
  int* flag = (int*)p;                  p += 16;
  __half* sup = (__half*)p;             p += (size_t)n_nodes * OUT_F * 2;
  int2* tmp = (int2*)p;                 p += (size_t)n_edges * 8;
  int2* pedge = (int2*)p;               p += (size_t)n_edges * 8;
  int* row_ptr = (int*)p;               p += (size_t)(n_nodes + 1) * 4;
  int* bcnt = (int*)p;                  p += (size_t)nbuck * 4;
  int* bptr = (int*)p;                  p += (size_t)(nbuck + 1) * 4;
  int* cnt2d = (int*)p;                 p += (size_t)nbuck * nblk * 4;
  int* off2d = (int*)p;                 p += (size_t)nbuck * nblk * 4;
  size_t need = (size_t)(p - (char*)d_ws);

  int ntiles = (n_nodes + 15) / 16;

  // GEMM (MFMA) + safety net
  hipMemsetAsync(flag, 0, 4, stream);
  gemm_mfma<<<(n_nodes + 127) / 128, 256, 0, stream>>>(x, w, sup, n_nodes);
  gemm_check<<<4, 256, 0, stream>>>(x, w, sup, flag, n_nodes);
  gemm_fixup<<<2048, 256, 0, stream>>>(x, w, sup, flag, n_nodes, ntiles);

  if (ws_size >= need && nbuck <= MAXB) {
    hist2<<<nblk, 256, 0, stream>>>(erow, cnt2d, n_edges, nbuck, nblk);
    rowsum<<<nbuck, 256, 0, stream>>>(cnt2d, bcnt, nblk);
    bucket_scan<<<1, 1024, 0, stream>>>(bcnt, bptr, nbuck);
    rowscan<<<nbuck, 256, 0, stream>>>(cnt2d, bptr, off2d, nblk);
    coarse_bin<<<nblk, 512, 0, stream>>>(erow, ecol, eval, off2d, tmp,
                                         n_edges, nbuck, nblk);
    fine_sort<<<nbuck, 256, 0, stream>>>(bptr, tmp, pedge, row_ptr, n_nodes, nbuck);
    spmm_gather<<<(n_nodes + 3) / 4, 256, 0, stream>>>(row_ptr, pedge, sup, bias,
                                                       out, n_nodes);
  } else {
    init_bias<<<(total + 255) / 256, 256, 0, stream>>>(out, bias, total);
    long long threads = (long long)n_edges * 64;
    spmm_scatter<<<(int)((threads + 255) / 256), 256, 0, stream>>>(erow, ecol, eval,
                                                                   sup, out, n_edges);
    relu_k<<<(total + 255) / 256, 256, 0, stream>>>(out, total);
  }
}

// Round 8
// 294.876 us; speedup vs baseline: 8.9751x; 1.2058x over previous
//
#include <hip/hip_runtime.h>
#include <hip/hip_fp16.h>

#define IN_F 256
#define OUT_F 128
#define RPB 128
#define LOG_RPB 7
#define MAXB 1024
#define CHUNK 8192

typedef __attribute__((ext_vector_type(8))) short short8;
typedef __attribute__((ext_vector_type(4))) float f32x4;

__device__ inline short bf16r(float f) {
  unsigned u = __float_as_uint(f);
  u += 0x7FFF + ((u >> 16) & 1);  // RNE
  return (short)(u >> 16);
}

// ---------------- K1: sup(fp16) = x @ W via bf16 MFMA -----------------------
__global__ __launch_bounds__(256) void gemm_mfma(const float* __restrict__ x,
                                                 const float* __restrict__ w,
                                                 __half* __restrict__ sup,
                                                 int n_nodes) {
  __shared__ short wlds[128 * 256];  // 64 KB: wlds[n][k] swizzled
  int t = threadIdx.x;
  for (int idx = t; idx < 256 * 128; idx += 256) {
    int k = idx >> 7;
    int n = idx & 127;
    int g = k >> 3;
    wlds[n * 256 + ((g ^ (n & 7)) << 3) + (k & 7)] = bf16r(w[idx]);
  }
  __syncthreads();

  int lane = t & 63;
  int wid = t >> 6;
  int wrow = (wid >> 1) * 64;
  int wcol = (wid & 1) * 64;
  int row_blk = blockIdx.x * 128;

  int arow[4];
#pragma unroll
  for (int mt = 0; mt < 4; ++mt)
    arow[mt] = min(row_blk + wrow + mt * 16 + (lane & 15), n_nodes - 1);
  int koff = (lane >> 4) * 8;

  f32x4 acc[4][4];
#pragma unroll
  for (int mt = 0; mt < 4; ++mt)
#pragma unroll
    for (int nt = 0; nt < 4; ++nt) acc[mt][nt] = (f32x4){0.f, 0.f, 0.f, 0.f};

#pragma unroll 2
  for (int kk = 0; kk < IN_F; kk += 32) {
    short8 af[4];
#pragma unroll
    for (int mt = 0; mt < 4; ++mt) {
      const float* px = x + (size_t)arow[mt] * IN_F + kk + koff;
      float4 p = *(const float4*)px;
      float4 q = *(const float4*)(px + 4);
      short8 a;
      a[0] = bf16r(p.x); a[1] = bf16r(p.y); a[2] = bf16r(p.z); a[3] = bf16r(p.w);
      a[4] = bf16r(q.x); a[5] = bf16r(q.y); a[6] = bf16r(q.z); a[7] = bf16r(q.w);
      af[mt] = a;
    }
    short8 bf[4];
    int g = (kk >> 3) + (lane >> 4);
#pragma unroll
    for (int nt = 0; nt < 4; ++nt) {
      int n = wcol + nt * 16 + (lane & 15);
      bf[nt] = *(const short8*)&wlds[n * 256 + ((g ^ (n & 7)) << 3)];
    }
#pragma unroll
    for (int mt = 0; mt < 4; ++mt)
#pragma unroll
      for (int nt = 0; nt < 4; ++nt)
        acc[mt][nt] = __builtin_amdgcn_mfma_f32_16x16x32_bf16(af[mt], bf[nt],
                                                              acc[mt][nt], 0, 0, 0);
  }

#pragma unroll
  for (int mt = 0; mt < 4; ++mt)
#pragma unroll
    for (int nt = 0; nt < 4; ++nt)
#pragma unroll
      for (int reg = 0; reg < 4; ++reg) {
        int grow = row_blk + wrow + mt * 16 + (lane >> 4) * 4 + reg;
        int gcol = wcol + nt * 16 + (lane & 15);
        if (grow < n_nodes)
          sup[(size_t)grow * OUT_F + gcol] = __float2half(acc[mt][nt][reg]);
      }
}

// ---------------- atomic-free CSR build -------------------------------------
__global__ __launch_bounds__(256) void hist2(const int* __restrict__ erow,
                                             int* __restrict__ cnt2d,
                                             int n_edges, int nbuck, int nblk) {
  __shared__ int h[MAXB];
  int t = threadIdx.x;
  for (int i = t; i < nbuck; i += 256) h[i] = 0;
  __syncthreads();
  int beg = blockIdx.x * CHUNK;
  int end = min(beg + CHUNK, n_edges);
  for (int e = beg + t; e < end; e += 256) atomicAdd(&h[erow[e] >> LOG_RPB], 1);
  __syncthreads();
  for (int i = t; i < nbuck; i += 256) cnt2d[(size_t)i * nblk + blockIdx.x] = h[i];
}

__global__ __launch_bounds__(256) void rowsum(const int* __restrict__ cnt2d,
                                              int* __restrict__ bcnt, int nblk) {
  __shared__ int red[256];
  int b = blockIdx.x;
  const int* row = cnt2d + (size_t)b * nblk;
  int t = threadIdx.x;
  int s = 0;
  for (int i = t; i < nblk; i += 256) s += row[i];
  red[t] = s;
  __syncthreads();
  for (int off = 128; off > 0; off >>= 1) {
    if (t < off) red[t] += red[t + off];
    __syncthreads();
  }
  if (t == 0) bcnt[b] = red[0];
}

__global__ __launch_bounds__(1024) void bucket_scan(const int* __restrict__ bcnt,
                                                    int* __restrict__ bptr, int nbuck) {
  __shared__ int sc[1024];
  int t = threadIdx.x;
  int v = (t < nbuck) ? bcnt[t] : 0;
  sc[t] = v;
  __syncthreads();
  for (int off = 1; off < 1024; off <<= 1) {
    int u = (t >= off) ? sc[t - off] : 0;
    __syncthreads();
    sc[t] += u;
    __syncthreads();
  }
  if (t < nbuck) bptr[t] = sc[t] - v;
  if (t == 1023) bptr[nbuck] = sc[1023];
}

__global__ __launch_bounds__(256) void rowscan(const int* __restrict__ cnt2d,
                                               const int* __restrict__ bptr,
                                               int* __restrict__ off2d, int nblk) {
  __shared__ int sc[256];
  int b = blockIdx.x;
  const int* row = cnt2d + (size_t)b * nblk;
  int* orow = off2d + (size_t)b * nblk;
  int t = threadIdx.x;
  int chunk = (nblk + 255) >> 8;
  int beg = t * chunk, end2 = min(beg + chunk, nblk);
  int s = 0;
  for (int i = beg; i < end2; ++i) s += row[i];
  sc[t] = s;
  __syncthreads();
  for (int off = 1; off < 256; off <<= 1) {
    int u = (t >= off) ? sc[t - off] : 0;
    __syncthreads();
    sc[t] += u;
    __syncthreads();
  }
  int run = sc[t] - s + bptr[b];
  for (int i = beg; i < end2; ++i) {
    orow[i] = run;
    run += row[i];
  }
}

__global__ __launch_bounds__(512) void coarse_bin(const int* __restrict__ erow,
                                                  const int* __restrict__ ecol,
                                                  const float* __restrict__ eval,
                                                  const int* __restrict__ off2d,
                                                  int2* __restrict__ tmp,
                                                  int n_edges, int nbuck, int nblk) {
  __shared__ int cnt[MAXB];
  __shared__ int base[MAXB];
  int t = threadIdx.x;
  for (int i = t; i < nbuck; i += 512) {
    cnt[i] = 0;
    base[i] = off2d[(size_t)i * nblk + blockIdx.x];
  }
  __syncthreads();
  int beg = blockIdx.x * CHUNK;
  int end = min(beg + CHUNK, n_edges);
  for (int e = beg + t; e < end; e += 512) {
    int r = erow[e];
    int b = r >> LOG_RPB;
    int pos = base[b] + atomicAdd(&cnt[b], 1);
    int2 pk;
    pk.x = ecol[e] | ((r & (RPB - 1)) << 17);
    pk.y = __float_as_int(eval[e]);
    tmp[pos] = pk;
  }
}

// ---------------- fine sort: bucket -> row-sorted pedge + row_ptr -----------
__global__ __launch_bounds__(256) void fine_sort(const int* __restrict__ bptr,
                                                 const int2* __restrict__ tmp,
                                                 int2* __restrict__ pedge,
                                                 int* __restrict__ row_ptr,
                                                 int n_nodes, int nbuck) {
  __shared__ int hist[RPB];
  __shared__ int sc[RPB];
  __shared__ int cur[RPB];
  int b = blockIdx.x;
  int row0 = b << LOG_RPB;
  int t = threadIdx.x;
  int bbeg = bptr[b];
  int bend = bptr[b + 1];

  if (t < RPB) hist[t] = 0;
  __syncthreads();
  for (int j = bbeg + t; j < bend; j += 256) atomicAdd(&hist[tmp[j].x >> 17], 1);
  __syncthreads();
  if (t < RPB) sc[t] = hist[t];
  __syncthreads();
  for (int off = 1; off < RPB; off <<= 1) {
    int u = (t < RPB && t >= off) ? sc[t - off] : 0;
    __syncthreads();
    if (t < RPB) sc[t] += u;
    __syncthreads();
  }
  if (t < RPB) {
    int st = bbeg + sc[t] - hist[t];
    cur[t] = st;
    if (row0 + t < n_nodes) row_ptr[row0 + t] = st;
  }
  __syncthreads();
  for (int j = bbeg + t; j < bend; j += 256) {
    int2 e = tmp[j];
    int rl = e.x >> 17;
    int pos = atomicAdd(&cur[rl], 1);
    int2 pk;
    pk.x = e.x & 0x1FFFF;
    pk.y = e.y;
    pedge[pos] = pk;
  }
  if (b == nbuck - 1 && t == 0) row_ptr[n_nodes] = bend;
}

// ---------------- gather: 2 edges/wave, 8 B/lane, cross-half combine --------
__global__ __launch_bounds__(256) void spmm_gather(const int* __restrict__ row_ptr,
                                                   const int2* __restrict__ pedge,
                                                   const __half* __restrict__ sup,
                                                   const float* __restrict__ bias,
                                                   float* __restrict__ out,
                                                   int n_nodes) {
  int r = blockIdx.x * 4 + (threadIdx.x >> 6);
  if (r >= n_nodes) return;
  int lane = threadIdx.x & 63;
  int h = lane >> 5;   // half-wave: which edge of the pair
  int sl = lane & 31;  // sub-lane: channels 4sl..4sl+3
  int beg = row_ptr[r];
  int end = row_ptr[r + 1];

  float4 a0 = {0.f, 0.f, 0.f, 0.f};
  float4 a1 = {0.f, 0.f, 0.f, 0.f};
  float4 a2 = {0.f, 0.f, 0.f, 0.f};
  float4 a3 = {0.f, 0.f, 0.f, 0.f};

  int j = beg + h;  // this half's edge stream, stride 2
  for (; j + 6 < end; j += 8) {
    int2 e0 = pedge[j];
    int2 e1 = pedge[j + 2];
    int2 e2 = pedge[j + 4];
    int2 e3 = pedge[j + 6];
    uint2 s0 = ((const uint2*)(sup + (size_t)e0.x * OUT_F))[sl];
    uint2 s1 = ((const uint2*)(sup + (size_t)e1.x * OUT_F))[sl];
    uint2 s2 = ((const uint2*)(sup + (size_t)e2.x * OUT_F))[sl];
    uint2 s3 = ((const uint2*)(sup + (size_t)e3.x * OUT_F))[sl];
    float v0 = __int_as_float(e0.y);
    float v1 = __int_as_float(e1.y);
    float v2 = __int_as_float(e2.y);
    float v3 = __int_as_float(e3.y);
    float2 p, q;
    p = __half22float2(*(__half2*)&s0.x); q = __half22float2(*(__half2*)&s0.y);
    a0.x = fmaf(p.x, v0, a0.x); a0.y = fmaf(p.y, v0, a0.y);
    a0.z = fmaf(q.x, v0, a0.z); a0.w = fmaf(q.y, v0, a0.w);
    p = __half22float2(*(__half2*)&s1.x); q = __half22float2(*(__half2*)&s1.y);
    a1.x = fmaf(p.x, v1, a1.x); a1.y = fmaf(p.y, v1, a1.y);
    a1.z = fmaf(q.x, v1, a1.z); a1.w = fmaf(q.y, v1, a1.w);
    p = __half22float2(*(__half2*)&s2.x); q = __half22float2(*(__half2*)&s2.y);
    a2.x = fmaf(p.x, v2, a2.x); a2.y = fmaf(p.y, v2, a2.y);
    a2.z = fmaf(q.x, v2, a2.z); a2.w = fmaf(q.y, v2, a2.w);
    p = __half22float2(*(__half2*)&s3.x); q = __half22float2(*(__half2*)&s3.y);
    a3.x = fmaf(p.x, v3, a3.x); a3.y = fmaf(p.y, v3, a3.y);
    a3.z = fmaf(q.x, v3, a3.z); a3.w = fmaf(q.y, v3, a3.w);
  }
  for (; j < end; j += 2) {
    int2 e0 = pedge[j];
    uint2 s0 = ((const uint2*)(sup + (size_t)e0.x * OUT_F))[sl];
    float v0 = __int_as_float(e0.y);
    float2 p = __half22float2(*(__half2*)&s0.x);
    float2 q = __half22float2(*(__half2*)&s0.y);
    a0.x = fmaf(p.x, v0, a0.x); a0.y = fmaf(p.y, v0, a0.y);
    a0.z = fmaf(q.x, v0, a0.z); a0.w = fmaf(q.y, v0, a0.w);
  }

  float4 f;
  f.x = (a0.x + a1.x) + (a2.x + a3.x);
  f.y = (a0.y + a1.y) + (a2.y + a3.y);
  f.z = (a0.z + a1.z) + (a2.z + a3.z);
  f.w = (a0.w + a1.w) + (a2.w + a3.w);
  // combine the two half-wave partial sums (lane <-> lane+32)
  f.x += __shfl_xor(f.x, 32);
  f.y += __shfl_xor(f.y, 32);
  f.z += __shfl_xor(f.z, 32);
  f.w += __shfl_xor(f.w, 32);

  if (h == 0) {
    float4 b = ((const float4*)bias)[sl];
    float4 o;
    o.x = fmaxf(f.x + b.x, 0.f);
    o.y = fmaxf(f.y + b.y, 0.f);
    o.z = fmaxf(f.z + b.z, 0.f);
    o.w = fmaxf(f.w + b.w, 0.f);
    ((float4*)(out + (size_t)r * OUT_F))[sl] = o;
  }
}

// ---------------- fallback (atomic scatter) ---------------------------------
__global__ __launch_bounds__(256) void init_bias(float* __restrict__ out,
                                                 const float* __restrict__ bias,
                                                 int total) {
  int i = blockIdx.x * 256 + threadIdx.x;
  if (i < total) out[i] = bias[i & (OUT_F - 1)];
}

__global__ __launch_bounds__(256) void spmm_scatter(const int* __restrict__ erow,
                                                    const int* __restrict__ ecol,
                                                    const float* __restrict__ eval,
                                                    const __half* __restrict__ sup,
                                                    float* __restrict__ out,
                                                    int n_edges) {
  long long t = (long long)blockIdx.x * 256 + threadIdx.x;
  int e = (int)(t >> 6);
  if (e >= n_edges) return;
  int lane = (int)(t & 63);
  int r = erow[e];
  int c = ecol[e];
  float v = eval[e];
  __half2 s = ((const __half2*)(sup + (size_t)c * OUT_F))[lane];
  float2 f = __half22float2(s);
  float* orow = out + (size_t)r * OUT_F + 2 * lane;
  unsafeAtomicAdd(orow + 0, f.x * v);
  unsafeAtomicAdd(orow + 1, f.y * v);
}

__global__ __launch_bounds__(256) void relu_k(float* __restrict__ out, int total) {
  int i = blockIdx.x * 256 + threadIdx.x;
  if (i < total) out[i] = fmaxf(out[i], 0.f);
}

extern "C" void kernel_launch(void* const* d_in, const int* in_sizes, int n_in,
                              void* d_out, int out_size, void* d_ws, size_t ws_size,
                              hipStream_t stream) {
  const float* x = (const float*)d_in[0];
  const int* erow = (const int*)d_in[1];
  const int* ecol = (const int*)d_in[2];
  const float* eval = (const float*)d_in[3];
  const float* w = (const float*)d_in[4];
  const float* bias = (const float*)d_in[5];
  float* out = (float*)d_out;

  int n_nodes = in_sizes[0] / IN_F;   // 100000
  int n_edges = in_sizes[1];          // 3200000
  int total = n_nodes * OUT_F;
  int nbuck = (n_nodes + RPB - 1) >> LOG_RPB;
  int nblk = (n_edges + CHUNK - 1) / CHUNK;

  // ws layout
  char* p = (char*)d_ws;
  __half* sup = (__half*)p;             p += (size_t)n_nodes * OUT_F * 2;
  int2* tmp = (int2*)p;                 p += (size_t)n_edges * 8;
  int2* pedge = (int2*)p;               p += (size_t)n_edges * 8;
  int* row_ptr = (int*)p;               p += (size_t)(n_nodes + 1) * 4;
  int* bcnt = (int*)p;                  p += (size_t)nbuck * 4;
  int* bptr = (int*)p;                  p += (size_t)(nbuck + 1) * 4;
  int* cnt2d = (int*)p;                 p += (size_t)nbuck * nblk * 4;
  int* off2d = (int*)p;                 p += (size_t)nbuck * nblk * 4;
  size_t need = (size_t)(p - (char*)d_ws);

  gemm_mfma<<<(n_nodes + 127) / 128, 256, 0, stream>>>(x, w, sup, n_nodes);

  if (ws_size >= need && nbuck <= MAXB) {
    hist2<<<nblk, 256, 0, stream>>>(erow, cnt2d, n_edges, nbuck, nblk);
    rowsum<<<nbuck, 256, 0, stream>>>(cnt2d, bcnt, nblk);
    bucket_scan<<<1, 1024, 0, stream>>>(bcnt, bptr, nbuck);
    rowscan<<<nbuck, 256, 0, stream>>>(cnt2d, bptr, off2d, nblk);
    coarse_bin<<<nblk, 512, 0, stream>>>(erow, ecol, eval, off2d, tmp,
                                         n_edges, nbuck, nblk);
    fine_sort<<<nbuck, 256, 0, stream>>>(bptr, tmp, pedge, row_ptr, n_nodes, nbuck);
    spmm_gather<<<(n_nodes + 3) / 4, 256, 0, stream>>>(row_ptr, pedge, sup, bias,
                                                       out, n_nodes);
  } else {
    init_bias<<<(total + 255) / 256, 256, 0, stream>>>(out, bias, total);
    long long threads = (long long)n_edges * 64;
    spmm_scatter<<<(int)((threads + 255) / 256), 256, 0, stream>>>(erow, ecol, eval,
                                                                   sup, out, n_edges);
    relu_k<<<(total + 255) / 256, 256, 0, stream>>>(out, total);
  }
}

// Round 9
// 261.681 us; speedup vs baseline: 10.1136x; 1.1269x over previous
//
#include <hip/hip_runtime.h>
#include <hip/hip_fp16.h>

#define IN_F 256
#define OUT_F 128
#define RPB 128
#define LOG_RPB 7
#define MAXB 1024
#define CHUNK 8192

typedef __attribute__((ext_vector_type(8))) short short8;
typedef __attribute__((ext_vector_type(4))) float f32x4;

__device__ inline short bf16r(float f) {
  unsigned u = __float_as_uint(f);
  u += 0x7FFF + ((u >> 16) & 1);  // RNE
  return (short)(u >> 16);
}

// ---------------- K1: sup(fp16) = x @ W via bf16 MFMA -----------------------
// 512 threads / 8 waves, tile 256 rows x 128 cols. W (bf16, 64 KB) in LDS,
// XOR-swizzled; amortized over 2x rows vs R8. Layouts HW-verified (R7/R8).
__global__ __launch_bounds__(512) void gemm_mfma(const float* __restrict__ x,
                                                 const float* __restrict__ w,
                                                 __half* __restrict__ sup,
                                                 int n_nodes) {
  __shared__ short wlds[128 * 256];  // 64 KB: wlds[n][k] swizzled
  int t = threadIdx.x;
  for (int idx = t; idx < 256 * 128; idx += 512) {
    int k = idx >> 7;
    int n = idx & 127;
    int g = k >> 3;
    wlds[n * 256 + ((g ^ (n & 7)) << 3) + (k & 7)] = bf16r(w[idx]);
  }
  __syncthreads();

  int lane = t & 63;
  int wid = t >> 6;                 // 0..7
  int wrow = (wid >> 1) * 64;       // 0,64,128,192
  int wcol = (wid & 1) * 64;        // 0,64
  int row_blk = blockIdx.x * 256;

  int arow[4];
#pragma unroll
  for (int mt = 0; mt < 4; ++mt)
    arow[mt] = min(row_blk + wrow + mt * 16 + (lane & 15), n_nodes - 1);
  int koff = (lane >> 4) * 8;

  f32x4 acc[4][4];
#pragma unroll
  for (int mt = 0; mt < 4; ++mt)
#pragma unroll
    for (int nt = 0; nt < 4; ++nt) acc[mt][nt] = (f32x4){0.f, 0.f, 0.f, 0.f};

#pragma unroll 2
  for (int kk = 0; kk < IN_F; kk += 32) {
    short8 af[4];
#pragma unroll
    for (int mt = 0; mt < 4; ++mt) {
      const float* px = x + (size_t)arow[mt] * IN_F + kk + koff;
      float4 p = *(const float4*)px;
      float4 q = *(const float4*)(px + 4);
      short8 a;
      a[0] = bf16r(p.x); a[1] = bf16r(p.y); a[2] = bf16r(p.z); a[3] = bf16r(p.w);
      a[4] = bf16r(q.x); a[5] = bf16r(q.y); a[6] = bf16r(q.z); a[7] = bf16r(q.w);
      af[mt] = a;
    }
    short8 bf[4];
    int g = (kk >> 3) + (lane >> 4);
#pragma unroll
    for (int nt = 0; nt < 4; ++nt) {
      int n = wcol + nt * 16 + (lane & 15);
      bf[nt] = *(const short8*)&wlds[n * 256 + ((g ^ (n & 7)) << 3)];
    }
#pragma unroll
    for (int mt = 0; mt < 4; ++mt)
#pragma unroll
      for (int nt = 0; nt < 4; ++nt)
        acc[mt][nt] = __builtin_amdgcn_mfma_f32_16x16x32_bf16(af[mt], bf[nt],
                                                              acc[mt][nt], 0, 0, 0);
  }

#pragma unroll
  for (int mt = 0; mt < 4; ++mt)
#pragma unroll
    for (int nt = 0; nt < 4; ++nt)
#pragma unroll
      for (int reg = 0; reg < 4; ++reg) {
        int grow = row_blk + wrow + mt * 16 + (lane >> 4) * 4 + reg;
        int gcol = wcol + nt * 16 + (lane & 15);
        if (grow < n_nodes)
          sup[(size_t)grow * OUT_F + gcol] = __float2half(acc[mt][nt][reg]);
      }
}

// ---------------- atomic-free CSR build -------------------------------------
__global__ __launch_bounds__(256) void hist2(const int* __restrict__ erow,
                                             int* __restrict__ cnt2d,
                                             int n_edges, int nbuck, int nblk) {
  __shared__ int h[MAXB];
  int t = threadIdx.x;
  for (int i = t; i < nbuck; i += 256) h[i] = 0;
  __syncthreads();
  int beg = blockIdx.x * CHUNK;
  int end = min(beg + CHUNK, n_edges);
  for (int e = beg + t; e < end; e += 256) atomicAdd(&h[erow[e] >> LOG_RPB], 1);
  __syncthreads();
  for (int i = t; i < nbuck; i += 256) cnt2d[(size_t)i * nblk + blockIdx.x] = h[i];
}

__global__ __launch_bounds__(256) void rowsum(const int* __restrict__ cnt2d,
                                              int* __restrict__ bcnt, int nblk) {
  __shared__ int red[256];
  int b = blockIdx.x;
  const int* row = cnt2d + (size_t)b * nblk;
  int t = threadIdx.x;
  int s = 0;
  for (int i = t; i < nblk; i += 256) s += row[i];
  red[t] = s;
  __syncthreads();
  for (int off = 128; off > 0; off >>= 1) {
    if (t < off) red[t] += red[t + off];
    __syncthreads();
  }
  if (t == 0) bcnt[b] = red[0];
}

__global__ __launch_bounds__(1024) void bucket_scan(const int* __restrict__ bcnt,
                                                    int* __restrict__ bptr, int nbuck) {
  __shared__ int sc[1024];
  int t = threadIdx.x;
  int v = (t < nbuck) ? bcnt[t] : 0;
  sc[t] = v;
  __syncthreads();
  for (int off = 1; off < 1024; off <<= 1) {
    int u = (t >= off) ? sc[t - off] : 0;
    __syncthreads();
    sc[t] += u;
    __syncthreads();
  }
  if (t < nbuck) bptr[t] = sc[t] - v;
  if (t == 1023) bptr[nbuck] = sc[1023];
}

__global__ __launch_bounds__(256) void rowscan(const int* __restrict__ cnt2d,
                                               const int* __restrict__ bptr,
                                               int* __restrict__ off2d, int nblk) {
  __shared__ int sc[256];
  int b = blockIdx.x;
  const int* row = cnt2d + (size_t)b * nblk;
  int* orow = off2d + (size_t)b * nblk;
  int t = threadIdx.x;
  int chunk = (nblk + 255) >> 8;
  int beg = t * chunk, end2 = min(beg + chunk, nblk);
  int s = 0;
  for (int i = beg; i < end2; ++i) s += row[i];
  sc[t] = s;
  __syncthreads();
  for (int off = 1; off < 256; off <<= 1) {
    int u = (t >= off) ? sc[t - off] : 0;
    __syncthreads();
    sc[t] += u;
    __syncthreads();
  }
  int run = sc[t] - s + bptr[b];
  for (int i = beg; i < end2; ++i) {
    orow[i] = run;
    run += row[i];
  }
}

__global__ __launch_bounds__(512) void coarse_bin(const int* __restrict__ erow,
                                                  const int* __restrict__ ecol,
                                                  const float* __restrict__ eval,
                                                  const int* __restrict__ off2d,
                                                  int2* __restrict__ tmp,
                                                  int n_edges, int nbuck, int nblk) {
  __shared__ int cnt[MAXB];
  __shared__ int base[MAXB];
  int t = threadIdx.x;
  for (int i = t; i < nbuck; i += 512) {
    cnt[i] = 0;
    base[i] = off2d[(size_t)i * nblk + blockIdx.x];
  }
  __syncthreads();
  int beg = blockIdx.x * CHUNK;
  int end = min(beg + CHUNK, n_edges);
  for (int e = beg + t; e < end; e += 512) {
    int r = erow[e];
    int b = r >> LOG_RPB;
    int pos = base[b] + atomicAdd(&cnt[b], 1);
    int2 pk;
    pk.x = ecol[e] | ((r & (RPB - 1)) << 17);
    pk.y = __float_as_int(eval[e]);
    tmp[pos] = pk;
  }
}

// ---------------- fine sort: bucket -> row-sorted packed pedge + row_ptr ----
// pedge[pos] = col(17 bits) | q15(val)<<17, val = q/32767.
__global__ __launch_bounds__(256) void fine_sort(const int* __restrict__ bptr,
                                                 const int2* __restrict__ tmp,
                                                 unsigned* __restrict__ pedge,
                                                 int* __restrict__ row_ptr,
                                                 int n_nodes, int nbuck) {
  __shared__ int hist[RPB];
  __shared__ int sc[RPB];
  __shared__ int cur[RPB];
  int b = blockIdx.x;
  int row0 = b << LOG_RPB;
  int t = threadIdx.x;
  int bbeg = bptr[b];
  int bend = bptr[b + 1];

  if (t < RPB) hist[t] = 0;
  __syncthreads();
  for (int j = bbeg + t; j < bend; j += 256) atomicAdd(&hist[tmp[j].x >> 17], 1);
  __syncthreads();
  if (t < RPB) sc[t] = hist[t];
  __syncthreads();
  for (int off = 1; off < RPB; off <<= 1) {
    int u = (t < RPB && t >= off) ? sc[t - off] : 0;
    __syncthreads();
    if (t < RPB) sc[t] += u;
    __syncthreads();
  }
  if (t < RPB) {
    int st = bbeg + sc[t] - hist[t];
    cur[t] = st;
    if (row0 + t < n_nodes) row_ptr[row0 + t] = st;
  }
  __syncthreads();
  for (int j = bbeg + t; j < bend; j += 256) {
    int2 e = tmp[j];
    int rl = e.x >> 17;
    int pos = atomicAdd(&cur[rl], 1);
    float v = __int_as_float(e.y);
    int q = (int)(v * 32767.f + 0.5f);
    q = min(max(q, 0), 32767);
    pedge[pos] = (unsigned)(e.x & 0x1FFFF) | ((unsigned)q << 17);
  }
  if (b == nbuck - 1 && t == 0) row_ptr[n_nodes] = bend;
}

// ---------------- gather: 2 edges/wave, 8 B/lane, cross-half combine --------
__global__ __launch_bounds__(256) void spmm_gather(const int* __restrict__ row_ptr,
                                                   const unsigned* __restrict__ pedge,
                                                   const __half* __restrict__ sup,
                                                   const float* __restrict__ bias,
                                                   float* __restrict__ out,
                                                   int n_nodes) {
  int r = blockIdx.x * 4 + (threadIdx.x >> 6);
  if (r >= n_nodes) return;
  int lane = threadIdx.x & 63;
  int h = lane >> 5;   // half-wave: which edge of the pair
  int sl = lane & 31;  // sub-lane: channels 4sl..4sl+3
  int beg = row_ptr[r];
  int end = row_ptr[r + 1];
  const float dq = 1.0f / 32767.0f;

  float4 a0 = {0.f, 0.f, 0.f, 0.f};
  float4 a1 = {0.f, 0.f, 0.f, 0.f};
  float4 a2 = {0.f, 0.f, 0.f, 0.f};
  float4 a3 = {0.f, 0.f, 0.f, 0.f};

  int j = beg + h;  // this half's edge stream, stride 2
  for (; j + 6 < end; j += 8) {
    unsigned e0 = pedge[j];
    unsigned e1 = pedge[j + 2];
    unsigned e2 = pedge[j + 4];
    unsigned e3 = pedge[j + 6];
    uint2 s0 = ((const uint2*)(sup + (size_t)(e0 & 0x1FFFF) * OUT_F))[sl];
    uint2 s1 = ((const uint2*)(sup + (size_t)(e1 & 0x1FFFF) * OUT_F))[sl];
    uint2 s2 = ((const uint2*)(sup + (size_t)(e2 & 0x1FFFF) * OUT_F))[sl];
    uint2 s3 = ((const uint2*)(sup + (size_t)(e3 & 0x1FFFF) * OUT_F))[sl];
    float v0 = (float)(e0 >> 17) * dq;
    float v1 = (float)(e1 >> 17) * dq;
    float v2 = (float)(e2 >> 17) * dq;
    float v3 = (float)(e3 >> 17) * dq;
    float2 p, q;
    p = __half22float2(*(__half2*)&s0.x); q = __half22float2(*(__half2*)&s0.y);
    a0.x = fmaf(p.x, v0, a0.x); a0.y = fmaf(p.y, v0, a0.y);
    a0.z = fmaf(q.x, v0, a0.z); a0.w = fmaf(q.y, v0, a0.w);
    p = __half22float2(*(__half2*)&s1.x); q = __half22float2(*(__half2*)&s1.y);
    a1.x = fmaf(p.x, v1, a1.x); a1.y = fmaf(p.y, v1, a1.y);
    a1.z = fmaf(q.x, v1, a1.z); a1.w = fmaf(q.y, v1, a1.w);
    p = __half22float2(*(__half2*)&s2.x); q = __half22float2(*(__half2*)&s2.y);
    a2.x = fmaf(p.x, v2, a2.x); a2.y = fmaf(p.y, v2, a2.y);
    a2.z = fmaf(q.x, v2, a2.z); a2.w = fmaf(q.y, v2, a2.w);
    p = __half22float2(*(__half2*)&s3.x); q = __half22float2(*(__half2*)&s3.y);
    a3.x = fmaf(p.x, v3, a3.x); a3.y = fmaf(p.y, v3, a3.y);
    a3.z = fmaf(q.x, v3, a3.z); a3.w = fmaf(q.y, v3, a3.w);
  }
  for (; j < end; j += 2) {
    unsigned e0 = pedge[j];
    uint2 s0 = ((const uint2*)(sup + (size_t)(e0 & 0x1FFFF) * OUT_F))[sl];
    float v0 = (float)(e0 >> 17) * dq;
    float2 p = __half22float2(*(__half2*)&s0.x);
    float2 q = __half22float2(*(__half2*)&s0.y);
    a0.x = fmaf(p.x, v0, a0.x); a0.y = fmaf(p.y, v0, a0.y);
    a0.z = fmaf(q.x, v0, a0.z); a0.w = fmaf(q.y, v0, a0.w);
  }

  float4 f;
  f.x = (a0.x + a1.x) + (a2.x + a3.x);
  f.y = (a0.y + a1.y) + (a2.y + a3.y);
  f.z = (a0.z + a1.z) + (a2.z + a3.z);
  f.w = (a0.w + a1.w) + (a2.w + a3.w);
  f.x += __shfl_xor(f.x, 32);
  f.y += __shfl_xor(f.y, 32);
  f.z += __shfl_xor(f.z, 32);
  f.w += __shfl_xor(f.w, 32);

  if (h == 0) {
    float4 b = ((const float4*)bias)[sl];
    float4 o;
    o.x = fmaxf(f.x + b.x, 0.f);
    o.y = fmaxf(f.y + b.y, 0.f);
    o.z = fmaxf(f.z + b.z, 0.f);
    o.w = fmaxf(f.w + b.w, 0.f);
    ((float4*)(out + (size_t)r * OUT_F))[sl] = o;
  }
}

// ---------------- fallback (atomic scatter) ---------------------------------
__global__ __launch_bounds__(256) void init_bias(float* __restrict__ out,
                                                 const float* __restrict__ bias,
                                                 int total) {
  int i = blockIdx.x * 256 + threadIdx.x;
  if (i < total) out[i] = bias[i & (OUT_F - 1)];
}

__global__ __launch_bounds__(256) void spmm_scatter(const int* __restrict__ erow,
                                                    const int* __restrict__ ecol,
                                                    const float* __restrict__ eval,
                                                    const __half* __restrict__ sup,
                                                    float* __restrict__ out,
                                                    int n_edges) {
  long long t = (long long)blockIdx.x * 256 + threadIdx.x;
  int e = (int)(t >> 6);
  if (e >= n_edges) return;
  int lane = (int)(t & 63);
  int r = erow[e];
  int c = ecol[e];
  float v = eval[e];
  __half2 s = ((const __half2*)(sup + (size_t)c * OUT_F))[lane];
  float2 f = __half22float2(s);
  float* orow = out + (size_t)r * OUT_F + 2 * lane;
  unsafeAtomicAdd(orow + 0, f.x * v);
  unsafeAtomicAdd(orow + 1, f.y * v);
}

__global__ __launch_bounds__(256) void relu_k(float* __restrict__ out, int total) {
  int i = blockIdx.x * 256 + threadIdx.x;
  if (i < total) out[i] = fmaxf(out[i], 0.f);
}

extern "C" void kernel_launch(void* const* d_in, const int* in_sizes, int n_in,
                              void* d_out, int out_size, void* d_ws, size_t ws_size,
                              hipStream_t stream) {
  const float* x = (const float*)d_in[0];
  const int* erow = (const int*)d_in[1];
  const int* ecol = (const int*)d_in[2];
  const float* eval = (const float*)d_in[3];
  const float* w = (const float*)d_in[4];
  const float* bias = (const float*)d_in[5];
  float* out = (float*)d_out;

  int n_nodes = in_sizes[0] / IN_F;   // 100000
  int n_edges = in_sizes[1];          // 3200000
  int total = n_nodes * OUT_F;
  int nbuck = (n_nodes + RPB - 1) >> LOG_RPB;
  int nblk = (n_edges + CHUNK - 1) / CHUNK;

  // ws layout
  char* p = (char*)d_ws;
  __half* sup = (__half*)p;             p += (size_t)n_nodes * OUT_F * 2;
  int2* tmp = (int2*)p;                 p += (size_t)n_edges * 8;
  unsigned* pedge = (unsigned*)p;       p += (size_t)n_edges * 4;
  int* row_ptr = (int*)p;               p += (size_t)(n_nodes + 1) * 4;
  int* bcnt = (int*)p;                  p += (size_t)nbuck * 4;
  int* bptr = (int*)p;                  p += (size_t)(nbuck + 1) * 4;
  int* cnt2d = (int*)p;                 p += (size_t)nbuck * nblk * 4;
  int* off2d = (int*)p;                 p += (size_t)nbuck * nblk * 4;
  size_t need = (size_t)(p - (char*)d_ws);

  gemm_mfma<<<(n_nodes + 255) / 256, 512, 0, stream>>>(x, w, sup, n_nodes);

  if (ws_size >= need && nbuck <= MAXB) {
    hist2<<<nblk, 256, 0, stream>>>(erow, cnt2d, n_edges, nbuck, nblk);
    rowsum<<<nbuck, 256, 0, stream>>>(cnt2d, bcnt, nblk);
    bucket_scan<<<1, 1024, 0, stream>>>(bcnt, bptr, nbuck);
    rowscan<<<nbuck, 256, 0, stream>>>(cnt2d, bptr, off2d, nblk);
    coarse_bin<<<nblk, 512, 0, stream>>>(erow, ecol, eval, off2d, tmp,
                                         n_edges, nbuck, nblk);
    fine_sort<<<nbuck, 256, 0, stream>>>(bptr, tmp, pedge, row_ptr, n_nodes, nbuck);
    spmm_gather<<<(n_nodes + 3) / 4, 256, 0, stream>>>(row_ptr, pedge, sup, bias,
                                                       out, n_nodes);
  } else {
    init_bias<<<(total + 255) / 256, 256, 0, stream>>>(out, bias, total);
    long long threads = (long long)n_edges * 64;
    spmm_scatter<<<(int)((threads + 255) / 256), 256, 0, stream>>>(erow, ecol, eval,
                                                                   sup, out, n_edges);
    relu_k<<<(total + 255) / 256, 256, 0, stream>>>(out, total);
  }
}

// Round 10
// 260.321 us; speedup vs baseline: 10.1665x; 1.0052x over previous
//
#include <hip/hip_runtime.h>
#include <hip/hip_fp16.h>

#define IN_F 256
#define OUT_F 128
#define RPB 64
#define LOG_RPB 6
#define MAXB 2048
#define CHUNK 8192
#define CAP 3072   // LDS edge capacity per bucket (mean 2048 + 22 sigma)

typedef __attribute__((ext_vector_type(8))) short short8;
typedef __attribute__((ext_vector_type(4))) float f32x4;

__device__ inline short bf16r(float f) {
  unsigned u = __float_as_uint(f);
  u += 0x7FFF + ((u >> 16) & 1);  // RNE
  return (short)(u >> 16);
}

// ---------------- K1: sup(fp16) = x @ W via bf16 MFMA -----------------------
__global__ __launch_bounds__(512) void gemm_mfma(const float* __restrict__ x,
                                                 const float* __restrict__ w,
                                                 __half* __restrict__ sup,
                                                 int n_nodes) {
  __shared__ short wlds[128 * 256];  // 64 KB
  int t = threadIdx.x;
  for (int idx = t; idx < 256 * 128; idx += 512) {
    int k = idx >> 7;
    int n = idx & 127;
    int g = k >> 3;
    wlds[n * 256 + ((g ^ (n & 7)) << 3) + (k & 7)] = bf16r(w[idx]);
  }
  __syncthreads();

  int lane = t & 63;
  int wid = t >> 6;
  int wrow = (wid >> 1) * 64;
  int wcol = (wid & 1) * 64;
  int row_blk = blockIdx.x * 256;

  int arow[4];
#pragma unroll
  for (int mt = 0; mt < 4; ++mt)
    arow[mt] = min(row_blk + wrow + mt * 16 + (lane & 15), n_nodes - 1);
  int koff = (lane >> 4) * 8;

  f32x4 acc[4][4];
#pragma unroll
  for (int mt = 0; mt < 4; ++mt)
#pragma unroll
    for (int nt = 0; nt < 4; ++nt) acc[mt][nt] = (f32x4){0.f, 0.f, 0.f, 0.f};

#pragma unroll 2
  for (int kk = 0; kk < IN_F; kk += 32) {
    short8 af[4];
#pragma unroll
    for (int mt = 0; mt < 4; ++mt) {
      const float* px = x + (size_t)arow[mt] * IN_F + kk + koff;
      float4 p = *(const float4*)px;
      float4 q = *(const float4*)(px + 4);
      short8 a;
      a[0] = bf16r(p.x); a[1] = bf16r(p.y); a[2] = bf16r(p.z); a[3] = bf16r(p.w);
      a[4] = bf16r(q.x); a[5] = bf16r(q.y); a[6] = bf16r(q.z); a[7] = bf16r(q.w);
      af[mt] = a;
    }
    short8 bf[4];
    int g = (kk >> 3) + (lane >> 4);
#pragma unroll
    for (int nt = 0; nt < 4; ++nt) {
      int n = wcol + nt * 16 + (lane & 15);
      bf[nt] = *(const short8*)&wlds[n * 256 + ((g ^ (n & 7)) << 3)];
    }
#pragma unroll
    for (int mt = 0; mt < 4; ++mt)
#pragma unroll
      for (int nt = 0; nt < 4; ++nt)
        acc[mt][nt] = __builtin_amdgcn_mfma_f32_16x16x32_bf16(af[mt], bf[nt],
                                                              acc[mt][nt], 0, 0, 0);
  }

#pragma unroll
  for (int mt = 0; mt < 4; ++mt)
#pragma unroll
    for (int nt = 0; nt < 4; ++nt)
#pragma unroll
      for (int reg = 0; reg < 4; ++reg) {
        int grow = row_blk + wrow + mt * 16 + (lane >> 4) * 4 + reg;
        int gcol = wcol + nt * 16 + (lane & 15);
        if (grow < n_nodes)
          sup[(size_t)grow * OUT_F + gcol] = __float2half(acc[mt][nt][reg]);
      }
}

// ---------------- atomic-free CSR build -------------------------------------
__global__ __launch_bounds__(256) void hist2(const int* __restrict__ erow,
                                             int* __restrict__ cnt2d,
                                             int n_edges, int nbuck, int nblk) {
  __shared__ int h[MAXB];
  int t = threadIdx.x;
  for (int i = t; i < nbuck; i += 256) h[i] = 0;
  __syncthreads();
  int beg = blockIdx.x * CHUNK;
  int end = min(beg + CHUNK, n_edges);
  for (int e = beg + t; e < end; e += 256) atomicAdd(&h[erow[e] >> LOG_RPB], 1);
  __syncthreads();
  for (int i = t; i < nbuck; i += 256) cnt2d[(size_t)i * nblk + blockIdx.x] = h[i];
}

__global__ __launch_bounds__(256) void rowsum(const int* __restrict__ cnt2d,
                                              int* __restrict__ bcnt, int nblk) {
  __shared__ int red[256];
  int b = blockIdx.x;
  const int* row = cnt2d + (size_t)b * nblk;
  int t = threadIdx.x;
  int s = 0;
  for (int i = t; i < nblk; i += 256) s += row[i];
  red[t] = s;
  __syncthreads();
  for (int off = 128; off > 0; off >>= 1) {
    if (t < off) red[t] += red[t + off];
    __syncthreads();
  }
  if (t == 0) bcnt[b] = red[0];
}

// 2 buckets per thread (nbuck <= 2048), proven in R5
__global__ __launch_bounds__(1024) void bucket_scan(const int* __restrict__ bcnt,
                                                    int* __restrict__ bptr, int nbuck) {
  __shared__ int sc[1024];
  int t = threadIdx.x;
  int i0 = 2 * t, i1 = 2 * t + 1;
  int c0 = (i0 < nbuck) ? bcnt[i0] : 0;
  int c1 = (i1 < nbuck) ? bcnt[i1] : 0;
  int s = c0 + c1;
  sc[t] = s;
  __syncthreads();
  for (int off = 1; off < 1024; off <<= 1) {
    int u = (t >= off) ? sc[t - off] : 0;
    __syncthreads();
    sc[t] += u;
    __syncthreads();
  }
  int run = sc[t] - s;
  if (i0 < nbuck) { bptr[i0] = run; run += c0; }
  if (i1 < nbuck) { bptr[i1] = run; run += c1; }
  if (t == 1023) bptr[nbuck] = sc[1023];
}

__global__ __launch_bounds__(256) void rowscan(const int* __restrict__ cnt2d,
                                               const int* __restrict__ bptr,
                                               int* __restrict__ off2d, int nblk) {
  __shared__ int sc[256];
  int b = blockIdx.x;
  const int* row = cnt2d + (size_t)b * nblk;
  int* orow = off2d + (size_t)b * nblk;
  int t = threadIdx.x;
  int chunk = (nblk + 255) >> 8;
  int beg = t * chunk, end2 = min(beg + chunk, nblk);
  int s = 0;
  for (int i = beg; i < end2; ++i) s += row[i];
  sc[t] = s;
  __syncthreads();
  for (int off = 1; off < 256; off <<= 1) {
    int u = (t >= off) ? sc[t - off] : 0;
    __syncthreads();
    sc[t] += u;
    __syncthreads();
  }
  int run = sc[t] - s + bptr[b];
  for (int i = beg; i < end2; ++i) {
    orow[i] = run;
    run += row[i];
  }
}

__global__ __launch_bounds__(512) void coarse_bin(const int* __restrict__ erow,
                                                  const int* __restrict__ ecol,
                                                  const float* __restrict__ eval,
                                                  const int* __restrict__ off2d,
                                                  int2* __restrict__ tmp,
                                                  int n_edges, int nbuck, int nblk) {
  __shared__ int cnt[MAXB];
  __shared__ int base[MAXB];
  int t = threadIdx.x;
  for (int i = t; i < nbuck; i += 512) {
    cnt[i] = 0;
    base[i] = off2d[(size_t)i * nblk + blockIdx.x];
  }
  __syncthreads();
  int beg = blockIdx.x * CHUNK;
  int end = min(beg + CHUNK, n_edges);
  for (int e = beg + t; e < end; e += 512) {
    int r = erow[e];
    int b = r >> LOG_RPB;
    int pos = base[b] + atomicAdd(&cnt[b], 1);
    int2 pk;
    pk.x = ecol[e] | ((r & (RPB - 1)) << 17);
    pk.y = __float_as_int(eval[e]);
    tmp[pos] = pk;
  }
}

// ---------------- fused: in-LDS counting sort + register gather -------------
// one block per 64-row bucket. Edges sorted into LDS (4 B packed col|q15),
// then row-per-wave register gather + bias + relu. Spill-safe past CAP.
__global__ __launch_bounds__(256) void sort_gather(const int* __restrict__ bptr,
                                                   const int2* __restrict__ tmp,
                                                   unsigned* __restrict__ spill,
                                                   const __half* __restrict__ sup,
                                                   const float* __restrict__ bias,
                                                   float* __restrict__ out,
                                                   int n_nodes) {
  __shared__ unsigned eL[CAP];
  __shared__ int hist[RPB];
  __shared__ int ex[RPB + 1];
  __shared__ int cur[RPB];
  int b = blockIdx.x;
  int row0 = b << LOG_RPB;
  int t = threadIdx.x;
  int bbeg = bptr[b];
  int bend = bptr[b + 1];
  int m = bend - bbeg;

  if (t < RPB) hist[t] = 0;
  __syncthreads();
  for (int j = bbeg + t; j < bend; j += 256) atomicAdd(&hist[tmp[j].x >> 17], 1);
  __syncthreads();
  if (t < RPB) ex[t] = hist[t];
  __syncthreads();
  for (int off = 1; off < RPB; off <<= 1) {
    int u = (t < RPB && t >= off) ? ex[t - off] : 0;
    __syncthreads();
    if (t < RPB) ex[t] += u;
    __syncthreads();
  }
  if (t < RPB) {
    int st = ex[t] - hist[t];  // exclusive, bucket-relative
    ex[t] = st;
    cur[t] = st;
  }
  if (t == 0) ex[RPB] = m;
  __syncthreads();
  // counting-sort scatter into LDS (int atomics only)
  for (int j = bbeg + t; j < bend; j += 256) {
    int2 e = tmp[j];
    int rl = e.x >> 17;
    int pos = atomicAdd(&cur[rl], 1);
    float v = __int_as_float(e.y);
    int q = min(max((int)(v * 32767.f + 0.5f), 0), 32767);
    unsigned pk = (unsigned)(e.x & 0x1FFFF) | ((unsigned)q << 17);
    if (pos < CAP) eL[pos] = pk;
    else spill[bbeg + pos] = pk;
  }
  __syncthreads();

  // row-per-wave register gather
  int lane = t & 63;
  int wv = t >> 6;
  int h = lane >> 5;   // half-wave edge index parity
  int sl = lane & 31;  // channels 4sl..4sl+3
  const float dq = 1.0f / 32767.0f;
  float4 bi = ((const float4*)bias)[sl];
  int nr = min(RPB, n_nodes - row0);

  for (int rl = wv; rl < nr; rl += 4) {
    int beg = ex[rl];
    int end = ex[rl + 1];
    float4 a0 = {0.f, 0.f, 0.f, 0.f};
    float4 a1 = {0.f, 0.f, 0.f, 0.f};
    float4 a2 = {0.f, 0.f, 0.f, 0.f};
    float4 a3 = {0.f, 0.f, 0.f, 0.f};

    int j = beg + h;
#define LOADE(J) (((J) < CAP) ? eL[(J)] : spill[bbeg + (J)])
    for (; j + 6 < end; j += 8) {
      unsigned e0 = LOADE(j);
      unsigned e1 = LOADE(j + 2);
      unsigned e2 = LOADE(j + 4);
      unsigned e3 = LOADE(j + 6);
      uint2 s0 = ((const uint2*)(sup + (size_t)(e0 & 0x1FFFF) * OUT_F))[sl];
      uint2 s1 = ((const uint2*)(sup + (size_t)(e1 & 0x1FFFF) * OUT_F))[sl];
      uint2 s2 = ((const uint2*)(sup + (size_t)(e2 & 0x1FFFF) * OUT_F))[sl];
      uint2 s3 = ((const uint2*)(sup + (size_t)(e3 & 0x1FFFF) * OUT_F))[sl];
      float v0 = (float)(e0 >> 17) * dq;
      float v1 = (float)(e1 >> 17) * dq;
      float v2 = (float)(e2 >> 17) * dq;
      float v3 = (float)(e3 >> 17) * dq;
      float2 p, q;
      p = __half22float2(*(__half2*)&s0.x); q = __half22float2(*(__half2*)&s0.y);
      a0.x = fmaf(p.x, v0, a0.x); a0.y = fmaf(p.y, v0, a0.y);
      a0.z = fmaf(q.x, v0, a0.z); a0.w = fmaf(q.y, v0, a0.w);
      p = __half22float2(*(__half2*)&s1.x); q = __half22float2(*(__half2*)&s1.y);
      a1.x = fmaf(p.x, v1, a1.x); a1.y = fmaf(p.y, v1, a1.y);
      a1.z = fmaf(q.x, v1, a1.z); a1.w = fmaf(q.y, v1, a1.w);
      p = __half22float2(*(__half2*)&s2.x); q = __half22float2(*(__half2*)&s2.y);
      a2.x = fmaf(p.x, v2, a2.x); a2.y = fmaf(p.y, v2, a2.y);
      a2.z = fmaf(q.x, v2, a2.z); a2.w = fmaf(q.y, v2, a2.w);
      p = __half22float2(*(__half2*)&s3.x); q = __half22float2(*(__half2*)&s3.y);
      a3.x = fmaf(p.x, v3, a3.x); a3.y = fmaf(p.y, v3, a3.y);
      a3.z = fmaf(q.x, v3, a3.z); a3.w = fmaf(q.y, v3, a3.w);
    }
    for (; j < end; j += 2) {
      unsigned e0 = LOADE(j);
      uint2 s0 = ((const uint2*)(sup + (size_t)(e0 & 0x1FFFF) * OUT_F))[sl];
      float v0 = (float)(e0 >> 17) * dq;
      float2 p = __half22float2(*(__half2*)&s0.x);
      float2 q = __half22float2(*(__half2*)&s0.y);
      a0.x = fmaf(p.x, v0, a0.x); a0.y = fmaf(p.y, v0, a0.y);
      a0.z = fmaf(q.x, v0, a0.z); a0.w = fmaf(q.y, v0, a0.w);
    }
#undef LOADE
    float4 f;
    f.x = (a0.x + a1.x) + (a2.x + a3.x);
    f.y = (a0.y + a1.y) + (a2.y + a3.y);
    f.z = (a0.z + a1.z) + (a2.z + a3.z);
    f.w = (a0.w + a1.w) + (a2.w + a3.w);
    f.x += __shfl_xor(f.x, 32);
    f.y += __shfl_xor(f.y, 32);
    f.z += __shfl_xor(f.z, 32);
    f.w += __shfl_xor(f.w, 32);
    if (h == 0) {
      float4 o;
      o.x = fmaxf(f.x + bi.x, 0.f);
      o.y = fmaxf(f.y + bi.y, 0.f);
      o.z = fmaxf(f.z + bi.z, 0.f);
      o.w = fmaxf(f.w + bi.w, 0.f);
      ((float4*)(out + (size_t)(row0 + rl) * OUT_F))[sl] = o;
    }
  }
}

// ---------------- fallback (atomic scatter) ---------------------------------
__global__ __launch_bounds__(256) void init_bias(float* __restrict__ out,
                                                 const float* __restrict__ bias,
                                                 int total) {
  int i = blockIdx.x * 256 + threadIdx.x;
  if (i < total) out[i] = bias[i & (OUT_F - 1)];
}

__global__ __launch_bounds__(256) void spmm_scatter(const int* __restrict__ erow,
                                                    const int* __restrict__ ecol,
                                                    const float* __restrict__ eval,
                                                    const __half* __restrict__ sup,
                                                    float* __restrict__ out,
                                                    int n_edges) {
  long long t = (long long)blockIdx.x * 256 + threadIdx.x;
  int e = (int)(t >> 6);
  if (e >= n_edges) return;
  int lane = (int)(t & 63);
  int r = erow[e];
  int c = ecol[e];
  float v = eval[e];
  __half2 s = ((const __half2*)(sup + (size_t)c * OUT_F))[lane];
  float2 f = __half22float2(s);
  float* orow = out + (size_t)r * OUT_F + 2 * lane;
  unsafeAtomicAdd(orow + 0, f.x * v);
  unsafeAtomicAdd(orow + 1, f.y * v);
}

__global__ __launch_bounds__(256) void relu_k(float* __restrict__ out, int total) {
  int i = blockIdx.x * 256 + threadIdx.x;
  if (i < total) out[i] = fmaxf(out[i], 0.f);
}

extern "C" void kernel_launch(void* const* d_in, const int* in_sizes, int n_in,
                              void* d_out, int out_size, void* d_ws, size_t ws_size,
                              hipStream_t stream) {
  const float* x = (const float*)d_in[0];
  const int* erow = (const int*)d_in[1];
  const int* ecol = (const int*)d_in[2];
  const float* eval = (const float*)d_in[3];
  const float* w = (const float*)d_in[4];
  const float* bias = (const float*)d_in[5];
  float* out = (float*)d_out;

  int n_nodes = in_sizes[0] / IN_F;   // 100000
  int n_edges = in_sizes[1];          // 3200000
  int total = n_nodes * OUT_F;
  int nbuck = (n_nodes + RPB - 1) >> LOG_RPB;
  int nblk = (n_edges + CHUNK - 1) / CHUNK;

  // ws layout
  char* p = (char*)d_ws;
  __half* sup = (__half*)p;             p += (size_t)n_nodes * OUT_F * 2;
  int2* tmp = (int2*)p;                 p += (size_t)n_edges * 8;
  unsigned* spill = (unsigned*)p;       p += (size_t)n_edges * 4;
  int* bcnt = (int*)p;                  p += (size_t)nbuck * 4;
  int* bptr = (int*)p;                  p += (size_t)(nbuck + 1) * 4;
  int* cnt2d = (int*)p;                 p += (size_t)nbuck * nblk * 4;
  int* off2d = (int*)p;                 p += (size_t)nbuck * nblk * 4;
  size_t need = (size_t)(p - (char*)d_ws);

  gemm_mfma<<<(n_nodes + 255) / 256, 512, 0, stream>>>(x, w, sup, n_nodes);

  if (ws_size >= need && nbuck <= MAXB) {
    hist2<<<nblk, 256, 0, stream>>>(erow, cnt2d, n_edges, nbuck, nblk);
    rowsum<<<nbuck, 256, 0, stream>>>(cnt2d, bcnt, nblk);
    bucket_scan<<<1, 1024, 0, stream>>>(bcnt, bptr, nbuck);
    rowscan<<<nbuck, 256, 0, stream>>>(cnt2d, bptr, off2d, nblk);
    coarse_bin<<<nblk, 512, 0, stream>>>(erow, ecol, eval, off2d, tmp,
                                         n_edges, nbuck, nblk);
    sort_gather<<<nbuck, 256, 0, stream>>>(bptr, tmp, spill, sup, bias, out,
                                           n_nodes);
  } else {
    init_bias<<<(total + 255) / 256, 256, 0, stream>>>(out, bias, total);
    long long threads = (long long)n_edges * 64;
    spmm_scatter<<<(int)((threads + 255) / 256), 256, 0, stream>>>(erow, ecol, eval,
                                                                   sup, out, n_edges);
    relu_k<<<(total + 255) / 256, 256, 0, stream>>>(out, total);
  }
}

// Round 11
// 239.386 us; speedup vs baseline: 11.0555x; 1.0875x over previous
//
#include <hip/hip_runtime.h>
#include <hip/hip_fp16.h>

#define IN_F 256
#define OUT_F 128
#define RPB 64
#define LOG_RPB 6
#define MAXB 2048
#define CHUNK 8192
#define CAP 3072   // LDS edge capacity per bucket (mean 2048 + 22 sigma)

typedef __attribute__((ext_vector_type(8))) short short8;
typedef __attribute__((ext_vector_type(4))) float f32x4;

__device__ inline short bf16r(float f) {
  unsigned u = __float_as_uint(f);
  u += 0x7FFF + ((u >> 16) & 1);  // RNE
  return (short)(u >> 16);
}

// packed edge word: col[0:17) | q9[17:26) | rowlocal[26:32)
#define COL_OF(e) ((e) & 0x1FFFFu)
#define Q9_OF(e)  (((e) >> 17) & 0x1FFu)
#define RL_OF(e)  ((e) >> 26)

// ---------------- K1: fused {bf16-MFMA GEMM | bucket histogram} -------------
// blocks [0,ngemm): sup = x@W, 256-row x 128-col tile, W in LDS (64 KB).
// blocks [ngemm,..): per-chunk bucket histogram into cnt2d (LDS aliased).
__global__ __launch_bounds__(512) void gemm_hist(const float* __restrict__ x,
                                                 const float* __restrict__ w,
                                                 __half* __restrict__ sup,
                                                 int n_nodes,
                                                 const int* __restrict__ erow,
                                                 int* __restrict__ cnt2d,
                                                 int n_edges, int nbuck, int nblk,
                                                 int ngemm) {
  __shared__ char smem[128 * 256 * 2];  // 64 KB, aliased by both paths
  int t = threadIdx.x;

  if ((int)blockIdx.x >= ngemm) {
    // ---- histogram path ----
    int* h = (int*)smem;
    int hb = blockIdx.x - ngemm;
    for (int i = t; i < nbuck; i += 512) h[i] = 0;
    __syncthreads();
    int beg = hb * CHUNK;
    int end = min(beg + CHUNK, n_edges);
    for (int e = beg + t; e < end; e += 512) atomicAdd(&h[erow[e] >> LOG_RPB], 1);
    __syncthreads();
    for (int i = t; i < nbuck; i += 512) cnt2d[(size_t)i * nblk + hb] = h[i];
    return;
  }

  // ---- GEMM path ----
  short* wlds = (short*)smem;  // wlds[n][k] swizzled
  for (int idx = t; idx < 256 * 128; idx += 512) {
    int k = idx >> 7;
    int n = idx & 127;
    int g = k >> 3;
    wlds[n * 256 + ((g ^ (n & 7)) << 3) + (k & 7)] = bf16r(w[idx]);
  }
  __syncthreads();

  int lane = t & 63;
  int wid = t >> 6;
  int wrow = (wid >> 1) * 64;
  int wcol = (wid & 1) * 64;
  int row_blk = blockIdx.x * 256;

  int arow[4];
#pragma unroll
  for (int mt = 0; mt < 4; ++mt)
    arow[mt] = min(row_blk + wrow + mt * 16 + (lane & 15), n_nodes - 1);
  int koff = (lane >> 4) * 8;

  f32x4 acc[4][4];
#pragma unroll
  for (int mt = 0; mt < 4; ++mt)
#pragma unroll
    for (int nt = 0; nt < 4; ++nt) acc[mt][nt] = (f32x4){0.f, 0.f, 0.f, 0.f};

#pragma unroll 2
  for (int kk = 0; kk < IN_F; kk += 32) {
    short8 af[4];
#pragma unroll
    for (int mt = 0; mt < 4; ++mt) {
      const float* px = x + (size_t)arow[mt] * IN_F + kk + koff;
      float4 p = *(const float4*)px;
      float4 q = *(const float4*)(px + 4);
      short8 a;
      a[0] = bf16r(p.x); a[1] = bf16r(p.y); a[2] = bf16r(p.z); a[3] = bf16r(p.w);
      a[4] = bf16r(q.x); a[5] = bf16r(q.y); a[6] = bf16r(q.z); a[7] = bf16r(q.w);
      af[mt] = a;
    }
    short8 bf[4];
    int g = (kk >> 3) + (lane >> 4);
#pragma unroll
    for (int nt = 0; nt < 4; ++nt) {
      int n = wcol + nt * 16 + (lane & 15);
      bf[nt] = *(const short8*)&wlds[n * 256 + ((g ^ (n & 7)) << 3)];
    }
#pragma unroll
    for (int mt = 0; mt < 4; ++mt)
#pragma unroll
      for (int nt = 0; nt < 4; ++nt)
        acc[mt][nt] = __builtin_amdgcn_mfma_f32_16x16x32_bf16(af[mt], bf[nt],
                                                              acc[mt][nt], 0, 0, 0);
  }

#pragma unroll
  for (int mt = 0; mt < 4; ++mt)
#pragma unroll
    for (int nt = 0; nt < 4; ++nt)
#pragma unroll
      for (int reg = 0; reg < 4; ++reg) {
        int grow = row_blk + wrow + mt * 16 + (lane >> 4) * 4 + reg;
        int gcol = wcol + nt * 16 + (lane & 15);
        if (grow < n_nodes)
          sup[(size_t)grow * OUT_F + gcol] = __float2half(acc[mt][nt][reg]);
      }
}

// ---------------- scans (atomic-free CSR build) ------------------------------
__global__ __launch_bounds__(256) void rowsum(const int* __restrict__ cnt2d,
                                              int* __restrict__ bcnt, int nblk) {
  __shared__ int red[256];
  int b = blockIdx.x;
  const int* row = cnt2d + (size_t)b * nblk;
  int t = threadIdx.x;
  int s = 0;
  for (int i = t; i < nblk; i += 256) s += row[i];
  red[t] = s;
  __syncthreads();
  for (int off = 128; off > 0; off >>= 1) {
    if (t < off) red[t] += red[t + off];
    __syncthreads();
  }
  if (t == 0) bcnt[b] = red[0];
}

__global__ __launch_bounds__(1024) void bucket_scan(const int* __restrict__ bcnt,
                                                    int* __restrict__ bptr, int nbuck) {
  __shared__ int sc[1024];
  int t = threadIdx.x;
  int i0 = 2 * t, i1 = 2 * t + 1;
  int c0 = (i0 < nbuck) ? bcnt[i0] : 0;
  int c1 = (i1 < nbuck) ? bcnt[i1] : 0;
  int s = c0 + c1;
  sc[t] = s;
  __syncthreads();
  for (int off = 1; off < 1024; off <<= 1) {
    int u = (t >= off) ? sc[t - off] : 0;
    __syncthreads();
    sc[t] += u;
    __syncthreads();
  }
  int run = sc[t] - s;
  if (i0 < nbuck) { bptr[i0] = run; run += c0; }
  if (i1 < nbuck) { bptr[i1] = run; run += c1; }
  if (t == 1023) bptr[nbuck] = sc[1023];
}

__global__ __launch_bounds__(256) void rowscan(const int* __restrict__ cnt2d,
                                               const int* __restrict__ bptr,
                                               int* __restrict__ off2d, int nblk) {
  __shared__ int sc[256];
  int b = blockIdx.x;
  const int* row = cnt2d + (size_t)b * nblk;
  int* orow = off2d + (size_t)b * nblk;
  int t = threadIdx.x;
  int chunk = (nblk + 255) >> 8;
  int beg = t * chunk, end2 = min(beg + chunk, nblk);
  int s = 0;
  for (int i = beg; i < end2; ++i) s += row[i];
  sc[t] = s;
  __syncthreads();
  for (int off = 1; off < 256; off <<= 1) {
    int u = (t >= off) ? sc[t - off] : 0;
    __syncthreads();
    sc[t] += u;
    __syncthreads();
  }
  int run = sc[t] - s + bptr[b];
  for (int i = beg; i < end2; ++i) {
    orow[i] = run;
    run += row[i];
  }
}

// ---------------- coarse bin: edges -> bucket-grouped packed 4B tmp ---------
__global__ __launch_bounds__(512) void coarse_bin(const int* __restrict__ erow,
                                                  const int* __restrict__ ecol,
                                                  const float* __restrict__ eval,
                                                  const int* __restrict__ off2d,
                                                  unsigned* __restrict__ tmp,
                                                  int n_edges, int nbuck, int nblk) {
  __shared__ int cnt[MAXB];
  __shared__ int base[MAXB];
  int t = threadIdx.x;
  for (int i = t; i < nbuck; i += 512) {
    cnt[i] = 0;
    base[i] = off2d[(size_t)i * nblk + blockIdx.x];
  }
  __syncthreads();
  int beg = blockIdx.x * CHUNK;
  int end = min(beg + CHUNK, n_edges);
  for (int e = beg + t; e < end; e += 512) {
    int r = erow[e];
    int b = r >> LOG_RPB;
    int pos = base[b] + atomicAdd(&cnt[b], 1);
    float v = eval[e];
    int q = min(max((int)(v * 511.f + 0.5f), 0), 511);
    tmp[pos] = (unsigned)ecol[e] | ((unsigned)q << 17) |
               ((unsigned)(r & (RPB - 1)) << 26);
  }
}

// ---------------- fused: in-LDS counting sort + quarter-wave gather ---------
__global__ __launch_bounds__(256) void sort_gather(const int* __restrict__ bptr,
                                                   const unsigned* __restrict__ tmp,
                                                   unsigned* __restrict__ spill,
                                                   const __half* __restrict__ sup,
                                                   const float* __restrict__ bias,
                                                   float* __restrict__ out,
                                                   int n_nodes) {
  __shared__ unsigned eL[CAP];
  __shared__ int hist[RPB];
  __shared__ int ex[RPB + 1];
  __shared__ int cur[RPB];
  int b = blockIdx.x;
  int row0 = b << LOG_RPB;
  int t = threadIdx.x;
  int bbeg = bptr[b];
  int bend = bptr[b + 1];
  int m = bend - bbeg;

  if (t < RPB) hist[t] = 0;
  __syncthreads();
  for (int j = bbeg + t; j < bend; j += 256) atomicAdd(&hist[RL_OF(tmp[j])], 1);
  __syncthreads();
  if (t < RPB) ex[t] = hist[t];
  __syncthreads();
  for (int off = 1; off < RPB; off <<= 1) {
    int u = (t < RPB && t >= off) ? ex[t - off] : 0;
    __syncthreads();
    if (t < RPB) ex[t] += u;
    __syncthreads();
  }
  if (t < RPB) {
    int st = ex[t] - hist[t];  // exclusive, bucket-relative
    ex[t] = st;
    cur[t] = st;
  }
  if (t == 0) ex[RPB] = m;
  __syncthreads();
  for (int j = bbeg + t; j < bend; j += 256) {
    unsigned e = tmp[j];
    int pos = atomicAdd(&cur[RL_OF(e)], 1);
    if (pos < CAP) eL[pos] = e;
    else spill[bbeg + pos] = e;
  }
  __syncthreads();

  // quarter-wave gather: qw = edge slot (0..3), sl = channel group (8 ch each)
  int lane = t & 63;
  int wv = t >> 6;
  int qw = lane >> 4;
  int sl = lane & 15;
  const float dq = 1.0f / 511.0f;
  float4 bi0 = ((const float4*)bias)[2 * sl + 0];
  float4 bi1 = ((const float4*)bias)[2 * sl + 1];
  int nr = min(RPB, n_nodes - row0);

#define LOADE(J) (((J) < CAP) ? eL[(J)] : spill[bbeg + (J)])
  for (int rl = wv; rl < nr; rl += 4) {
    int beg = ex[rl];
    int end = ex[rl + 1];
    float a0[8] = {0.f, 0.f, 0.f, 0.f, 0.f, 0.f, 0.f, 0.f};
    float a1[8] = {0.f, 0.f, 0.f, 0.f, 0.f, 0.f, 0.f, 0.f};

    int j = beg + qw;
    for (; j + 4 < end; j += 8) {
      unsigned e0 = LOADE(j);
      unsigned e1 = LOADE(j + 4);
      uint4 s0 = ((const uint4*)(sup + (size_t)COL_OF(e0) * OUT_F))[sl];
      uint4 s1 = ((const uint4*)(sup + (size_t)COL_OF(e1) * OUT_F))[sl];
      float v0 = (float)Q9_OF(e0) * dq;
      float v1 = (float)Q9_OF(e1) * dq;
      float2 p;
      p = __half22float2(*(__half2*)&s0.x); a0[0] = fmaf(p.x, v0, a0[0]); a0[1] = fmaf(p.y, v0, a0[1]);
      p = __half22float2(*(__half2*)&s0.y); a0[2] = fmaf(p.x, v0, a0[2]); a0[3] = fmaf(p.y, v0, a0[3]);
      p = __half22float2(*(__half2*)&s0.z); a0[4] = fmaf(p.x, v0, a0[4]); a0[5] = fmaf(p.y, v0, a0[5]);
      p = __half22float2(*(__half2*)&s0.w); a0[6] = fmaf(p.x, v0, a0[6]); a0[7] = fmaf(p.y, v0, a0[7]);
      p = __half22float2(*(__half2*)&s1.x); a1[0] = fmaf(p.x, v1, a1[0]); a1[1] = fmaf(p.y, v1, a1[1]);
      p = __half22float2(*(__half2*)&s1.y); a1[2] = fmaf(p.x, v1, a1[2]); a1[3] = fmaf(p.y, v1, a1[3]);
      p = __half22float2(*(__half2*)&s1.z); a1[4] = fmaf(p.x, v1, a1[4]); a1[5] = fmaf(p.y, v1, a1[5]);
      p = __half22float2(*(__half2*)&s1.w); a1[6] = fmaf(p.x, v1, a1[6]); a1[7] = fmaf(p.y, v1, a1[7]);
    }
    if (j < end) {
      unsigned e0 = LOADE(j);
      uint4 s0 = ((const uint4*)(sup + (size_t)COL_OF(e0) * OUT_F))[sl];
      float v0 = (float)Q9_OF(e0) * dq;
      float2 p;
      p = __half22float2(*(__half2*)&s0.x); a0[0] = fmaf(p.x, v0, a0[0]); a0[1] = fmaf(p.y, v0, a0[1]);
      p = __half22float2(*(__half2*)&s0.y); a0[2] = fmaf(p.x, v0, a0[2]); a0[3] = fmaf(p.y, v0, a0[3]);
      p = __half22float2(*(__half2*)&s0.z); a0[4] = fmaf(p.x, v0, a0[4]); a0[5] = fmaf(p.y, v0, a0[5]);
      p = __half22float2(*(__half2*)&s0.w); a0[6] = fmaf(p.x, v0, a0[6]); a0[7] = fmaf(p.y, v0, a0[7]);
    }

    float r[8];
#pragma unroll
    for (int i = 0; i < 8; ++i) {
      r[i] = a0[i] + a1[i];
      r[i] += __shfl_xor(r[i], 16);
      r[i] += __shfl_xor(r[i], 32);
    }
    if (qw == 0) {
      float4 o0, o1;
      o0.x = fmaxf(r[0] + bi0.x, 0.f);
      o0.y = fmaxf(r[1] + bi0.y, 0.f);
      o0.z = fmaxf(r[2] + bi0.z, 0.f);
      o0.w = fmaxf(r[3] + bi0.w, 0.f);
      o1.x = fmaxf(r[4] + bi1.x, 0.f);
      o1.y = fmaxf(r[5] + bi1.y, 0.f);
      o1.z = fmaxf(r[6] + bi1.z, 0.f);
      o1.w = fmaxf(r[7] + bi1.w, 0.f);
      float4* orow = (float4*)(out + (size_t)(row0 + rl) * OUT_F);
      orow[2 * sl + 0] = o0;
      orow[2 * sl + 1] = o1;
    }
  }
#undef LOADE
}

// ---------------- fallback (atomic scatter) ---------------------------------
__global__ __launch_bounds__(512) void gemm_mfma_only(const float* __restrict__ x,
                                                      const float* __restrict__ w,
                                                      __half* __restrict__ sup,
                                                      int n_nodes) {
  // used only on fallback path; same as gemm path of gemm_hist
  __shared__ short wlds[128 * 256];
  int t = threadIdx.x;
  for (int idx = t; idx < 256 * 128; idx += 512) {
    int k = idx >> 7;
    int n = idx & 127;
    int g = k >> 3;
    wlds[n * 256 + ((g ^ (n & 7)) << 3) + (k & 7)] = bf16r(w[idx]);
  }
  __syncthreads();
  int lane = t & 63;
  int wid = t >> 6;
  int wrow = (wid >> 1) * 64;
  int wcol = (wid & 1) * 64;
  int row_blk = blockIdx.x * 256;
  int arow[4];
#pragma unroll
  for (int mt = 0; mt < 4; ++mt)
    arow[mt] = min(row_blk + wrow + mt * 16 + (lane & 15), n_nodes - 1);
  int koff = (lane >> 4) * 8;
  f32x4 acc[4][4];
#pragma unroll
  for (int mt = 0; mt < 4; ++mt)
#pragma unroll
    for (int nt = 0; nt < 4; ++nt) acc[mt][nt] = (f32x4){0.f, 0.f, 0.f, 0.f};
#pragma unroll 2
  for (int kk = 0; kk < IN_F; kk += 32) {
    short8 af[4];
#pragma unroll
    for (int mt = 0; mt < 4; ++mt) {
      const float* px = x + (size_t)arow[mt] * IN_F + kk + koff;
      float4 p = *(const float4*)px;
      float4 q = *(const float4*)(px + 4);
      short8 a;
      a[0] = bf16r(p.x); a[1] = bf16r(p.y); a[2] = bf16r(p.z); a[3] = bf16r(p.w);
      a[4] = bf16r(q.x); a[5] = bf16r(q.y); a[6] = bf16r(q.z); a[7] = bf16r(q.w);
      af[mt] = a;
    }
    short8 bf[4];
    int g = (kk >> 3) + (lane >> 4);
#pragma unroll
    for (int nt = 0; nt < 4; ++nt) {
      int n = wcol + nt * 16 + (lane & 15);
      bf[nt] = *(const short8*)&wlds[n * 256 + ((g ^ (n & 7)) << 3)];
    }
#pragma unroll
    for (int mt = 0; mt < 4; ++mt)
#pragma unroll
      for (int nt = 0; nt < 4; ++nt)
        acc[mt][nt] = __builtin_amdgcn_mfma_f32_16x16x32_bf16(af[mt], bf[nt],
                                                              acc[mt][nt], 0, 0, 0);
  }
#pragma unroll
  for (int mt = 0; mt < 4; ++mt)
#pragma unroll
    for (int nt = 0; nt < 4; ++nt)
#pragma unroll
      for (int reg = 0; reg < 4; ++reg) {
        int grow = row_blk + wrow + mt * 16 + (lane >> 4) * 4 + reg;
        int gcol = wcol + nt * 16 + (lane & 15);
        if (grow < n_nodes)
          sup[(size_t)grow * OUT_F + gcol] = __float2half(acc[mt][nt][reg]);
      }
}

__global__ __launch_bounds__(256) void init_bias(float* __restrict__ out,
                                                 const float* __restrict__ bias,
                                                 int total) {
  int i = blockIdx.x * 256 + threadIdx.x;
  if (i < total) out[i] = bias[i & (OUT_F - 1)];
}

__global__ __launch_bounds__(256) void spmm_scatter(const int* __restrict__ erow,
                                                    const int* __restrict__ ecol,
                                                    const float* __restrict__ eval,
                                                    const __half* __restrict__ sup,
                                                    float* __restrict__ out,
                                                    int n_edges) {
  long long t = (long long)blockIdx.x * 256 + threadIdx.x;
  int e = (int)(t >> 6);
  if (e >= n_edges) return;
  int lane = (int)(t & 63);
  int r = erow[e];
  int c = ecol[e];
  float v = eval[e];
  __half2 s = ((const __half2*)(sup + (size_t)c * OUT_F))[lane];
  float2 f = __half22float2(s);
  float* orow = out + (size_t)r * OUT_F + 2 * lane;
  unsafeAtomicAdd(orow + 0, f.x * v);
  unsafeAtomicAdd(orow + 1, f.y * v);
}

__global__ __launch_bounds__(256) void relu_k(float* __restrict__ out, int total) {
  int i = blockIdx.x * 256 + threadIdx.x;
  if (i < total) out[i] = fmaxf(out[i], 0.f);
}

extern "C" void kernel_launch(void* const* d_in, const int* in_sizes, int n_in,
                              void* d_out, int out_size, void* d_ws, size_t ws_size,
                              hipStream_t stream) {
  const float* x = (const float*)d_in[0];
  const int* erow = (const int*)d_in[1];
  const int* ecol = (const int*)d_in[2];
  const float* eval = (const float*)d_in[3];
  const float* w = (const float*)d_in[4];
  const float* bias = (const float*)d_in[5];
  float* out = (float*)d_out;

  int n_nodes = in_sizes[0] / IN_F;   // 100000
  int n_edges = in_sizes[1];          // 3200000
  int total = n_nodes * OUT_F;
  int nbuck = (n_nodes + RPB - 1) >> LOG_RPB;
  int nblk = (n_edges + CHUNK - 1) / CHUNK;
  int ngemm = (n_nodes + 255) / 256;

  // ws layout
  char* p = (char*)d_ws;
  __half* sup = (__half*)p;             p += (size_t)n_nodes * OUT_F * 2;
  unsigned* tmp = (unsigned*)p;         p += (size_t)n_edges * 4;
  unsigned* spill = (unsigned*)p;       p += (size_t)n_edges * 4;
  int* bcnt = (int*)p;                  p += (size_t)nbuck * 4;
  int* bptr = (int*)p;                  p += (size_t)(nbuck + 1) * 4;
  int* cnt2d = (int*)p;                 p += (size_t)nbuck * nblk * 4;
  int* off2d = (int*)p;                 p += (size_t)nbuck * nblk * 4;
  size_t need = (size_t)(p - (char*)d_ws);

  if (ws_size >= need && nbuck <= MAXB) {
    gemm_hist<<<ngemm + nblk, 512, 0, stream>>>(x, w, sup, n_nodes, erow, cnt2d,
                                                n_edges, nbuck, nblk, ngemm);
    rowsum<<<nbuck, 256, 0, stream>>>(cnt2d, bcnt, nblk);
    bucket_scan<<<1, 1024, 0, stream>>>(bcnt, bptr, nbuck);
    rowscan<<<nbuck, 256, 0, stream>>>(cnt2d, bptr, off2d, nblk);
    coarse_bin<<<nblk, 512, 0, stream>>>(erow, ecol, eval, off2d, tmp,
                                         n_edges, nbuck, nblk);
    sort_gather<<<nbuck, 256, 0, stream>>>(bptr, tmp, spill, sup, bias, out,
                                           n_nodes);
  } else {
    gemm_mfma_only<<<ngemm, 512, 0, stream>>>(x, w, sup, n_nodes);
    init_bias<<<(total + 255) / 256, 256, 0, stream>>>(out, bias, total);
    long long threads = (long long)n_edges * 64;
    spmm_scatter<<<(int)((threads + 255) / 256), 256, 0, stream>>>(erow, ecol, eval,
                                                                   sup, out, n_edges);
    relu_k<<<(total + 255) / 256, 256, 0, stream>>>(out, total);
  }
}